// Round 15
// baseline (301.360 us; speedup 1.0000x reference)
//
#include <hip/hip_runtime.h>
#include <hip/hip_fp16.h>

// Problem constants (match reference file)
#define NN 100000
#define NE 1600000
#define NG 64

// dst-bucketing for the CSR build
#define BSHIFT 7
#define BUCKW (1 << BSHIFT)                 // 128 nodes per bucket
#define NBUCK ((NN + BUCKW - 1) >> BSHIFT)  // 782
#define BIN_CHUNK 8192
#define NDEGC 64                            // degree classes for the node sort

// ---- fp16 8-wide helpers (activations stored fp16, math in fp32) ----
union H8 { float4 f4; __half2 h2[4]; };
__device__ __forceinline__ void h8_to_f(const H8& h, float* f) {
    float2 a = __half22float2(h.h2[0]);
    float2 b = __half22float2(h.h2[1]);
    float2 c = __half22float2(h.h2[2]);
    float2 d = __half22float2(h.h2[3]);
    f[0]=a.x; f[1]=a.y; f[2]=b.x; f[3]=b.y; f[4]=c.x; f[5]=c.y; f[6]=d.x; f[7]=d.y;
}
__device__ __forceinline__ H8 f_to_h8(const float* f) {
    H8 h;
    h.h2[0] = __floats2half2_rn(f[0], f[1]);
    h.h2[1] = __floats2half2_rn(f[2], f[3]);
    h.h2[2] = __floats2half2_rn(f[4], f[5]);
    h.h2[3] = __floats2half2_rn(f[6], f[7]);
    return h;
}

// ---------------- bucket histogram (LDS-aggregated) ----------------
__global__ __launch_bounds__(256) void bucket_hist_kernel(const int* __restrict__ dst,
                                                          int* __restrict__ bucket_cnt, int E) {
    __shared__ int h[NBUCK];
    for (int i = threadIdx.x; i < NBUCK; i += 256) h[i] = 0;
    __syncthreads();
    int stride = gridDim.x * 256;
    for (int e = blockIdx.x * 256 + threadIdx.x; e < E; e += stride)
        atomicAdd(&h[dst[e] >> BSHIFT], 1);
    __syncthreads();
    for (int i = threadIdx.x; i < NBUCK; i += 256)
        if (h[i]) atomicAdd(&bucket_cnt[i], h[i]);
}

// ---------------- bucket scan: single block ----------------
__global__ void bucket_scan_kernel(const int* __restrict__ bcnt, int* __restrict__ boff,
                                   int* __restrict__ bcur) {
    __shared__ int buf[2][1024];
    int t = threadIdx.x;
    int v = (t < NBUCK) ? bcnt[t] : 0;
    buf[0][t] = v;
    __syncthreads();
    int cur = 0;
    for (int off = 1; off < 1024; off <<= 1) {
        int x = buf[cur][t];
        if (t >= off) x += buf[cur][t - off];
        buf[cur ^ 1][t] = x;
        __syncthreads();
        cur ^= 1;
    }
    if (t < NBUCK) {
        int e = buf[cur][t] - v;
        boff[t] = e;
        bcur[t] = e;
    }
}

// ---------------- bin edges by dst-bucket; packed (src<<7)|dst_low ----------------
__global__ __launch_bounds__(256) void bin_kernel(const int* __restrict__ src,
                                                  const int* __restrict__ dst,
                                                  int* __restrict__ bcur,
                                                  unsigned* __restrict__ binned, int E) {
    __shared__ int h[NBUCK];
    __shared__ int cur[NBUCK];
    for (int i = threadIdx.x; i < NBUCK; i += 256) h[i] = 0;
    __syncthreads();
    int base = blockIdx.x * BIN_CHUNK;
    int end = base + BIN_CHUNK; if (end > E) end = E;
    for (int e = base + threadIdx.x; e < end; e += 256)
        atomicAdd(&h[dst[e] >> BSHIFT], 1);
    __syncthreads();
    for (int i = threadIdx.x; i < NBUCK; i += 256) {
        int c = h[i];
        cur[i] = c ? atomicAdd(&bcur[i], c) : 0;   // reserve contiguous sub-range
    }
    __syncthreads();
    for (int e = base + threadIdx.x; e < end; e += 256) {
        unsigned s = (unsigned)src[e], d = (unsigned)dst[e];
        int pos = atomicAdd(&cur[d >> BSHIFT], 1);
        binned[pos] = (s << BSHIFT) | (d & (BUCKW - 1));
    }
}

// ---------------- degree + dinv from binned edges ----------------
__global__ __launch_bounds__(256) void deg_dinv_kernel(const unsigned* __restrict__ binned,
                                                       const int* __restrict__ bucket_off,
                                                       const int* __restrict__ bucket_cnt,
                                                       int* __restrict__ deg,
                                                       float* __restrict__ dinv, int n) {
    __shared__ int ldeg[BUCKW];
    int b = blockIdx.x;
    for (int i = threadIdx.x; i < BUCKW; i += 256) ldeg[i] = 0;
    __syncthreads();
    int start = bucket_off[b], cnt = bucket_cnt[b];
    for (int k = threadIdx.x; k < cnt; k += 256)
        atomicAdd(&ldeg[binned[start + k] & (BUCKW - 1)], 1);
    __syncthreads();
    int v0 = b << BSHIFT;
    for (int i = threadIdx.x; i < BUCKW; i += 256) {
        int v = v0 + i;
        if (v < n) {
            int dg = ldeg[i];
            deg[v] = dg;
            dinv[v] = rsqrtf((float)dg + 1.0f);   // +1 = self loop
        }
    }
}

// ---------------- node scan (3 phases) ----------------
__global__ void scan1_kernel(const int* __restrict__ cntin, int* __restrict__ excl,
                             int* __restrict__ bsum, int n) {
    __shared__ int buf[2][1024];
    int t = threadIdx.x;
    int gid = blockIdx.x * 1024 + t;
    int v = (gid < n) ? cntin[gid] : 0;
    buf[0][t] = v;
    __syncthreads();
    int cur = 0;
    for (int off = 1; off < 1024; off <<= 1) {
        int x = buf[cur][t];
        if (t >= off) x += buf[cur][t - off];
        buf[cur ^ 1][t] = x;
        __syncthreads();
        cur ^= 1;
    }
    int incl = buf[cur][t];
    if (gid < n) excl[gid] = incl - v;
    if (t == 1023) bsum[blockIdx.x] = incl;
}

__global__ void scan2_kernel(int* __restrict__ bsum, int nb) {
    __shared__ int buf[2][128];
    int t = threadIdx.x;
    int v = (t < nb) ? bsum[t] : 0;
    buf[0][t] = v;
    __syncthreads();
    int cur = 0;
    for (int off = 1; off < 128; off <<= 1) {
        int x = buf[cur][t];
        if (t >= off) x += buf[cur][t - off];
        buf[cur ^ 1][t] = x;
        __syncthreads();
        cur ^= 1;
    }
    if (t < nb) bsum[t] = buf[cur][t] - v;
}

__global__ void scan3_kernel(int* __restrict__ excl, const int* __restrict__ bsum, int n) {
    int gid = blockIdx.x * blockDim.x + threadIdx.x;
    if (gid < n) excl[gid] += bsum[gid >> 10];
}

// ---------------- final CSR placement ----------------
__global__ __launch_bounds__(256) void build2_kernel(const unsigned* __restrict__ binned,
                                                     const int* __restrict__ bucket_off,
                                                     const int* __restrict__ bucket_cnt,
                                                     const int* __restrict__ roff,
                                                     int* __restrict__ csr_src, int n) {
    __shared__ int lcur[BUCKW];
    int b = blockIdx.x;
    int v0 = b << BSHIFT;
    for (int i = threadIdx.x; i < BUCKW; i += 256) {
        int v = v0 + i;
        lcur[i] = (v < n) ? roff[v] : 0;
    }
    __syncthreads();
    int start = bucket_off[b], cnt = bucket_cnt[b];
    for (int k = threadIdx.x; k < cnt; k += 256) {
        unsigned e = binned[start + k];
        int pos = atomicAdd(&lcur[e & (BUCKW - 1)], 1);
        csr_src[pos] = (int)(e >> BSHIFT);
    }
}

// ---------------- degree-class counting sort: perm of nodes by degree ----------------
__global__ __launch_bounds__(256) void dhist_kernel(const int* __restrict__ deg,
                                                    int* __restrict__ dhist, int n) {
    __shared__ int h[NDEGC];
    int t = threadIdx.x;
    if (t < NDEGC) h[t] = 0;
    __syncthreads();
    int v = blockIdx.x * 256 + t;
    if (v < n) atomicAdd(&h[min(deg[v], NDEGC - 1)], 1);
    __syncthreads();
    if (t < NDEGC && h[t]) atomicAdd(&dhist[t], h[t]);
}

__global__ void dscan_kernel(const int* __restrict__ dhist, int* __restrict__ dcur) {
    __shared__ int buf[2][NDEGC];
    int t = threadIdx.x;      // 64 threads
    int v = dhist[t];
    buf[0][t] = v;
    __syncthreads();
    int cur = 0;
    for (int off = 1; off < NDEGC; off <<= 1) {
        int x = buf[cur][t];
        if (t >= off) x += buf[cur][t - off];
        buf[cur ^ 1][t] = x;
        __syncthreads();
        cur ^= 1;
    }
    dcur[t] = buf[cur][t] - v;    // exclusive
}

__global__ __launch_bounds__(256) void dplace_kernel(const int* __restrict__ deg,
                                                     int* __restrict__ dcur,
                                                     int* __restrict__ perm, int n) {
    __shared__ int h[NDEGC];
    __shared__ int cur[NDEGC];
    int t = threadIdx.x;
    if (t < NDEGC) h[t] = 0;
    __syncthreads();
    int v = blockIdx.x * 256 + t;
    int dc = -1;
    if (v < n) { dc = min(deg[v], NDEGC - 1); atomicAdd(&h[dc], 1); }
    __syncthreads();
    if (t < NDEGC) { int c = h[t]; cur[t] = c ? atomicAdd(&dcur[t], c) : 0; }
    __syncthreads();
    if (v < n) {
        int pos = atomicAdd(&cur[dc], 1);
        perm[pos] = v;
    }
}

// ---------------- layer-1 aggregation fused with prescale (perm order) ----------------
// T[v] = dinv[v] * (dinv[v]*x[v] + sum_in dinv[s]*x[s]);  G=2 threads/node
__global__ void agg8_kernel(const float* __restrict__ x, const int* __restrict__ row_off,
                            const int* __restrict__ deg, const float* __restrict__ dinv,
                            const int* __restrict__ csr_src, const int* __restrict__ perm,
                            float2* __restrict__ out, int n) {
    int idx = blockIdx.x * blockDim.x + threadIdx.x;
    if (idx >= n * 2) return;
    int v = perm[idx >> 1];
    int c = idx & 1;
    const float4* h4 = (const float4*)x;
    float dvv = dinv[v];
    float4 self = h4[(size_t)v * 2 + c];
    float4 acc = make_float4(self.x * dvv, self.y * dvv, self.z * dvv, self.w * dvv);
    int start = row_off[v], cnt = deg[v];
    const int* __restrict__ row = csr_src + start;
    int j = 0;
    for (; j + 4 <= cnt; j += 4) {
        int s0 = row[j], s1 = row[j + 1], s2 = row[j + 2], s3 = row[j + 3];
        float d0 = dinv[s0], d1 = dinv[s1], d2 = dinv[s2], d3 = dinv[s3];
        float4 a0 = h4[(size_t)s0 * 2 + c];
        float4 a1 = h4[(size_t)s1 * 2 + c];
        float4 a2 = h4[(size_t)s2 * 2 + c];
        float4 a3 = h4[(size_t)s3 * 2 + c];
        acc.x += (a0.x * d0 + a1.x * d1) + (a2.x * d2 + a3.x * d3);
        acc.y += (a0.y * d0 + a1.y * d1) + (a2.y * d2 + a3.y * d3);
        acc.z += (a0.z * d0 + a1.z * d1) + (a2.z * d2 + a3.z * d3);
        acc.w += (a0.w * d0 + a1.w * d1) + (a2.w * d2 + a3.w * d3);
    }
    for (; j < cnt; ++j) {
        int s = row[j];
        float ds = dinv[s];
        float4 a = h4[(size_t)s * 2 + c];
        acc.x += a.x * ds; acc.y += a.y * ds; acc.z += a.z * ds; acc.w += a.w * ds;
    }
    union { float2 f2; __half2 h2[2]; } u;
    u.h2[0] = __floats2half2_rn(acc.x * dvv, acc.y * dvv);
    u.h2[1] = __floats2half2_rn(acc.z * dvv, acc.w * dvv);
    out[(size_t)v * 2 + c] = u.f2;
}

// ---------------- fp16 aggregation (perm order) ----------------
template<int FIN>
__global__ void agg_h_kernel(const float4* __restrict__ hs, const int* __restrict__ row_off,
                             const int* __restrict__ deg, const float* __restrict__ dinv,
                             const int* __restrict__ csr_src, const int* __restrict__ perm,
                             float4* __restrict__ out, int n) {
    constexpr int G = FIN / 8;
    int idx = blockIdx.x * blockDim.x + threadIdx.x;
    if (idx >= n * G) return;
    int v = perm[idx / G];
    int c = idx % G;
    float a[8];
    { H8 h; h.f4 = hs[(size_t)v * G + c]; h8_to_f(h, a); }
    int start = row_off[v], cnt = deg[v];
    const int* __restrict__ row = csr_src + start;
    int j = 0;
    for (; j + 8 <= cnt; j += 8) {
        H8 hh[8];
#pragma unroll
        for (int q = 0; q < 8; ++q) hh[q].f4 = hs[(size_t)row[j + q] * G + c];
#pragma unroll
        for (int q = 0; q < 8; ++q) {
            float f[8]; h8_to_f(hh[q], f);
#pragma unroll
            for (int k = 0; k < 8; ++k) a[k] += f[k];
        }
    }
    for (; j + 4 <= cnt; j += 4) {
        H8 h0, h1, h2, h3;
        h0.f4 = hs[(size_t)row[j] * G + c];
        h1.f4 = hs[(size_t)row[j + 1] * G + c];
        h2.f4 = hs[(size_t)row[j + 2] * G + c];
        h3.f4 = hs[(size_t)row[j + 3] * G + c];
        float f0[8], f1[8], f2[8], f3[8];
        h8_to_f(h0, f0); h8_to_f(h1, f1); h8_to_f(h2, f2); h8_to_f(h3, f3);
#pragma unroll
        for (int k = 0; k < 8; ++k) a[k] += (f0[k] + f1[k]) + (f2[k] + f3[k]);
    }
    for (; j < cnt; ++j) {
        H8 h; h.f4 = hs[(size_t)row[j] * G + c];
        float f[8]; h8_to_f(h, f);
#pragma unroll
        for (int k = 0; k < 8; ++k) a[k] += f[k];
    }
    float dv = dinv[v];
#pragma unroll
    for (int k = 0; k < 8; ++k) a[k] *= dv;
    H8 o = f_to_h8(a);
    out[(size_t)v * G + c] = o.f4;
}

// ---------------- fused matmul + bias + prelu; fp16 in/out, fp32 math ----------------
template<int FIN, int FOUT, bool SCALE>
__global__ __launch_bounds__(256) void matmul_kernel(
    const float4* __restrict__ tin, const float* __restrict__ W,
    const float* __restrict__ bias, const float* __restrict__ slope,
    const float* __restrict__ dinv, float2* __restrict__ hout, int n) {
    constexpr int TPN = FOUT / 4;            // threads per node (4 outputs each)
    constexpr int NPB = (256 / TPN) * 4;     // nodes per block
    __shared__ float4 Wl[FIN * TPN];
    const float4* Wg = (const float4*)W;
    for (int i = threadIdx.x; i < FIN * TPN; i += 256) Wl[i] = Wg[i];
    __syncthreads();
    int t = threadIdx.x;
    int grp = t / TPN;
    int f4 = t % TPN;
    int v0 = blockIdx.x * NPB + grp * 4;
    float s = slope ? *slope : 1.0f;
    float4 bv = ((const float4*)bias)[f4];
    float4 acc[4];
#pragma unroll
    for (int nn = 0; nn < 4; ++nn) acc[nn] = bv;
#pragma unroll
    for (int i = 0; i < FIN; i += 8) {
        float r[4][8];
#pragma unroll
        for (int nn = 0; nn < 4; ++nn) {
            int v = v0 + nn;
            H8 h;
            h.f4 = (v < n) ? tin[(size_t)v * (FIN / 8) + (i >> 3)]
                           : make_float4(0.f, 0.f, 0.f, 0.f);
            h8_to_f(h, r[nn]);
        }
#pragma unroll
        for (int k = 0; k < 8; ++k) {
            float4 wv = Wl[(i + k) * TPN + f4];
#pragma unroll
            for (int nn = 0; nn < 4; ++nn) {
                float rk = r[nn][k];
                acc[nn].x += wv.x * rk;
                acc[nn].y += wv.y * rk;
                acc[nn].z += wv.z * rk;
                acc[nn].w += wv.w * rk;
            }
        }
    }
#pragma unroll
    for (int nn = 0; nn < 4; ++nn) {
        int v = v0 + nn;
        if (v < n) {
            float m = SCALE ? dinv[v] : 1.0f;
            float ox = (fmaxf(acc[nn].x, 0.f) + s * fminf(acc[nn].x, 0.f)) * m;
            float oy = (fmaxf(acc[nn].y, 0.f) + s * fminf(acc[nn].y, 0.f)) * m;
            float oz = (fmaxf(acc[nn].z, 0.f) + s * fminf(acc[nn].z, 0.f)) * m;
            float ow = (fmaxf(acc[nn].w, 0.f) + s * fminf(acc[nn].w, 0.f)) * m;
            union { float2 f2; __half2 h2[2]; } u;
            u.h2[0] = __floats2half2_rn(ox, oy);
            u.h2[1] = __floats2half2_rn(oz, ow);
            hout[(size_t)v * TPN + f4] = u.f2;
        }
    }
}

// ---------------- makeM: M = W4 @ Wlin (64x4), bb = b4 @ Wlin + blin ----------------
__global__ __launch_bounds__(256) void makeM_kernel(
    const float* __restrict__ W4, const float* __restrict__ b4,
    const float* __restrict__ Wlin, const float* __restrict__ blin,
    float* __restrict__ M, float* __restrict__ bb) {
    int t = threadIdx.x;          // 256 = 64 * 4
    int k = t >> 2, c = t & 3;
    float m = 0.f;
    for (int j = 0; j < 128; ++j) m += W4[k * 128 + j] * Wlin[j * 4 + c];
    M[k * 4 + c] = m;
    if (t < 4) {
        float v = blin[t];
        for (int j = 0; j < 128; ++j) v += b4[j] * Wlin[j * 4 + t];
        bb[t] = v;
    }
}

// ---------------- layer-3 matmul fused with z-projection (shuffle-reduced) ------------
__global__ __launch_bounds__(256) void matmul_z_kernel(
    const float4* __restrict__ tin, const float* __restrict__ W,
    const float* __restrict__ bias, const float* __restrict__ slope,
    const float* __restrict__ dinv, const float* __restrict__ M,
    float4* __restrict__ z, int n) {
    constexpr int FIN = 32, FOUT = 64, TPN = FOUT / 4, NPB = 64;
    __shared__ float4 Wl[FIN * TPN];           // 8 KB
    __shared__ float4 Ml[FOUT];                // 1 KB
    const float4* Wg = (const float4*)W;
    for (int i = threadIdx.x; i < FIN * TPN; i += 256) Wl[i] = Wg[i];
    if (threadIdx.x < FOUT) Ml[threadIdx.x] = ((const float4*)M)[threadIdx.x];
    __syncthreads();
    int t = threadIdx.x;
    int grp = t / TPN;
    int f4 = t % TPN;
    int v0 = blockIdx.x * NPB + grp * 4;
    float s = *slope;
    float4 bv = ((const float4*)bias)[f4];
    float4 acc[4];
#pragma unroll
    for (int nn = 0; nn < 4; ++nn) acc[nn] = bv;
#pragma unroll
    for (int i = 0; i < FIN; i += 8) {
        float r[4][8];
#pragma unroll
        for (int nn = 0; nn < 4; ++nn) {
            int v = v0 + nn;
            H8 h;
            h.f4 = (v < n) ? tin[(size_t)v * (FIN / 8) + (i >> 3)]
                           : make_float4(0.f, 0.f, 0.f, 0.f);
            h8_to_f(h, r[nn]);
        }
#pragma unroll
        for (int k = 0; k < 8; ++k) {
            float4 wv = Wl[(i + k) * TPN + f4];
#pragma unroll
            for (int nn = 0; nn < 4; ++nn) {
                float rk = r[nn][k];
                acc[nn].x += wv.x * rk;
                acc[nn].y += wv.y * rk;
                acc[nn].z += wv.z * rk;
                acc[nn].w += wv.w * rk;
            }
        }
    }
    float4 m0 = Ml[f4 * 4 + 0];
    float4 m1 = Ml[f4 * 4 + 1];
    float4 m2 = Ml[f4 * 4 + 2];
    float4 m3 = Ml[f4 * 4 + 3];
#pragma unroll
    for (int nn = 0; nn < 4; ++nn) {
        int v = v0 + nn;
        float dvm = (v < n) ? dinv[v] : 0.f;
        float ox = (fmaxf(acc[nn].x, 0.f) + s * fminf(acc[nn].x, 0.f)) * dvm;
        float oy = (fmaxf(acc[nn].y, 0.f) + s * fminf(acc[nn].y, 0.f)) * dvm;
        float oz = (fmaxf(acc[nn].z, 0.f) + s * fminf(acc[nn].z, 0.f)) * dvm;
        float ow = (fmaxf(acc[nn].w, 0.f) + s * fminf(acc[nn].w, 0.f)) * dvm;
        float px = ox * m0.x + oy * m1.x + oz * m2.x + ow * m3.x;
        float py = ox * m0.y + oy * m1.y + oz * m2.y + ow * m3.y;
        float pz = ox * m0.z + oy * m1.z + oz * m2.z + ow * m3.z;
        float pw = ox * m0.w + oy * m1.w + oz * m2.w + ow * m3.w;
#pragma unroll
        for (int mask = 8; mask >= 1; mask >>= 1) {
            px += __shfl_xor(px, mask, 16);
            py += __shfl_xor(py, mask, 16);
            pz += __shfl_xor(pz, mask, 16);
            pw += __shfl_xor(pw, mask, 16);
        }
        if (f4 == 0 && v < n) z[v] = make_float4(px, py, pz, pw);
    }
}

// ---------------- layer-4 aggregation + pooling in z-space (wave-reduced) --------------
__global__ __launch_bounds__(256) void aggpool4_kernel(
    const float4* __restrict__ z, const int* __restrict__ row_off,
    const int* __restrict__ deg, const float* __restrict__ dinv,
    const int* __restrict__ csr_src, const int* __restrict__ batch,
    float* __restrict__ sums, float* __restrict__ cnt, int n) {
    __shared__ float lacc[NG * 4];
    __shared__ float lcnt[NG];
    int tid = threadIdx.x;
    if (tid < NG * 4) lacc[tid] = 0.f;
    if (tid < NG) lcnt[tid] = 0.f;
    __syncthreads();
    int v = blockIdx.x * 256 + tid;
    bool valid = (v < n);
    float cx = 0.f, cy = 0.f, cz = 0.f, cw = 0.f, rc = 0.f;
    int g = -1;
    if (valid) {
        float4 acc = z[v];
        int start = row_off[v], dcnt = deg[v];
        const int* __restrict__ row = csr_src + start;
        int j = 0;
        for (; j + 4 <= dcnt; j += 4) {
            float4 a0 = z[row[j]];
            float4 a1 = z[row[j + 1]];
            float4 a2 = z[row[j + 2]];
            float4 a3 = z[row[j + 3]];
            acc.x += (a0.x + a1.x) + (a2.x + a3.x);
            acc.y += (a0.y + a1.y) + (a2.y + a3.y);
            acc.z += (a0.z + a1.z) + (a2.z + a3.z);
            acc.w += (a0.w + a1.w) + (a2.w + a3.w);
        }
        for (; j < dcnt; ++j) {
            float4 a = z[row[j]];
            acc.x += a.x; acc.y += a.y; acc.z += a.z; acc.w += a.w;
        }
        float dv = dinv[v];
        cx = acc.x * dv; cy = acc.y * dv; cz = acc.z * dv; cw = acc.w * dv;
        rc = 1.f;
        g = batch[v];
    }
    int g0 = __shfl(g, 0, 64);
    if (__all(g == g0 || !valid)) {
#pragma unroll
        for (int mask = 32; mask >= 1; mask >>= 1) {
            cx += __shfl_xor(cx, mask, 64);
            cy += __shfl_xor(cy, mask, 64);
            cz += __shfl_xor(cz, mask, 64);
            cw += __shfl_xor(cw, mask, 64);
            rc += __shfl_xor(rc, mask, 64);
        }
        if ((tid & 63) == 0) {
            float* lp = &lacc[g0 * 4];
            atomicAdd(lp + 0, cx); atomicAdd(lp + 1, cy);
            atomicAdd(lp + 2, cz); atomicAdd(lp + 3, cw);
            atomicAdd(&lcnt[g0], rc);
        }
    } else if (valid) {
        float* lp = &lacc[g * 4];
        atomicAdd(lp + 0, cx); atomicAdd(lp + 1, cy);
        atomicAdd(lp + 2, cz); atomicAdd(lp + 3, cw);
        atomicAdd(&lcnt[g], 1.f);
    }
    __syncthreads();
    if (tid < NG * 4) {
        float val = lacc[tid];
        if (val != 0.f) atomicAdd(&sums[tid], val);
    }
    if (tid < NG) {
        float val = lcnt[tid];
        if (val != 0.f) atomicAdd(&cnt[tid], val);
    }
}

// ---------------- head: out[g][c] = sums[g][c]/cnt[g] + bb[c] ----------------
__global__ void head_kernel(const float* __restrict__ sums, const float* __restrict__ cnt,
                            const float* __restrict__ bb, float* __restrict__ out) {
    int t = threadIdx.x;          // 256 = 64 graphs * 4 classes
    int g = t >> 2, c = t & 3;
    out[t] = sums[t] / fmaxf(cnt[g], 1.f) + bb[c];
}

extern "C" void kernel_launch(void* const* d_in, const int* in_sizes, int n_in,
                              void* d_out, int out_size, void* d_ws, size_t ws_size,
                              hipStream_t stream) {
    const float* x    = (const float*)d_in[0];
    const int* esrc   = (const int*)d_in[1];
    const int* edst   = (const int*)d_in[2];
    const int* batch  = (const int*)d_in[3];
    const float* W1 = (const float*)d_in[4],  *b1 = (const float*)d_in[5];
    const float* W2 = (const float*)d_in[6],  *b2 = (const float*)d_in[7];
    const float* W3 = (const float*)d_in[8],  *b3 = (const float*)d_in[9];
    const float* W4 = (const float*)d_in[10], *b4 = (const float*)d_in[11];
    const float* a1 = (const float*)d_in[12];
    const float* a2 = (const float*)d_in[13];
    const float* a3 = (const float*)d_in[14];
    const float* Wlin = (const float*)d_in[15], *blin = (const float*)d_in[16];
    float* out = (float*)d_out;

    const int N = NN, E = NE;
    const int NB = (N + 1023) / 1024;                   // node-scan blocks (98)
    const int NBIN = (E + BIN_CHUNK - 1) / BIN_CHUNK;   // 196
    const int NBLK = (N + 255) / 256;                   // 391

    // workspace carve-up
    char* w = (char*)d_ws;
    size_t off = 0;
    auto alloc = [&](size_t bytes) { size_t r = off; off += (bytes + 255) & ~(size_t)255; return r; };
    size_t o_bcnt  = alloc((size_t)NBUCK * 4);      // needs zero
    size_t o_pool  = alloc((size_t)NG * 4 * 4);     // needs zero
    size_t o_cnt   = alloc((size_t)NG * 4);         // needs zero
    size_t o_dhist = alloc((size_t)NDEGC * 4);      // needs zero
    size_t zero_bytes = off;
    size_t o_deg  = alloc((size_t)N * 4);
    size_t o_dinv = alloc((size_t)N * 4);
    size_t o_roff = alloc((size_t)N * 4);
    size_t o_perm = alloc((size_t)N * 4);
    size_t o_boff = alloc((size_t)NBUCK * 4);
    size_t o_bcur = alloc((size_t)NBUCK * 4);
    size_t o_bsum = alloc((size_t)128 * 4);
    size_t o_dcur = alloc((size_t)NDEGC * 4);
    size_t o_csrc = alloc((size_t)E * 4);
    size_t o_bin  = alloc((size_t)E * 4);          // packed (src<<7)|dst_low
    size_t o_A    = alloc((size_t)N * 32 * 2);     // activations fp16 (max 32 halfs)
    size_t o_T    = alloc((size_t)N * 32 * 2);     // agg output fp16 (max 32 halfs)
    size_t o_z    = alloc((size_t)N * 4 * 4);      // z projections (float4/node)
    size_t o_M    = alloc((size_t)64 * 4 * 4);     // W4@Wlin
    size_t o_bb   = alloc((size_t)4 * 4);          // b4@Wlin + blin
    (void)ws_size;
    int*      bcnt   = (int*)(w + o_bcnt);
    float*    pool   = (float*)(w + o_pool);
    float*    cnt    = (float*)(w + o_cnt);
    int*      dhist  = (int*)(w + o_dhist);
    int*      deg    = (int*)(w + o_deg);
    float*    dinv   = (float*)(w + o_dinv);
    int*      roff   = (int*)(w + o_roff);
    int*      perm   = (int*)(w + o_perm);
    int*      boff   = (int*)(w + o_boff);
    int*      bcur   = (int*)(w + o_bcur);
    int*      bsum   = (int*)(w + o_bsum);
    int*      dcur   = (int*)(w + o_dcur);
    int*      csrc   = (int*)(w + o_csrc);
    unsigned* binned = (unsigned*)(w + o_bin);
    char*     A      = (char*)(w + o_A);
    char*     T      = (char*)(w + o_T);
    float4*   z      = (float4*)(w + o_z);
    float*    M      = (float*)(w + o_M);
    float*    bb     = (float*)(w + o_bb);

    hipMemsetAsync(w, 0, zero_bytes, stream);

    // ---- head constants (independent; launch early) ----
    makeM_kernel<<<1, 256, 0, stream>>>(W4, b4, Wlin, blin, M, bb);

    // ---- CSR build via dst-bucket binning (once, reused by all 4 layers) ----
    bucket_hist_kernel<<<256, 256, 0, stream>>>(edst, bcnt, E);
    bucket_scan_kernel<<<1, 1024, 0, stream>>>(bcnt, boff, bcur);
    bin_kernel<<<NBIN, 256, 0, stream>>>(esrc, edst, bcur, binned, E);
    deg_dinv_kernel<<<NBUCK, 256, 0, stream>>>(binned, boff, bcnt, deg, dinv, N);
    scan1_kernel<<<NB, 1024, 0, stream>>>(deg, roff, bsum, N);
    scan2_kernel<<<1, 128, 0, stream>>>(bsum, NB);
    scan3_kernel<<<(N + 255) / 256, 256, 0, stream>>>(roff, bsum, N);
    build2_kernel<<<NBUCK, 256, 0, stream>>>(binned, boff, bcnt, roff, csrc, N);

    // ---- degree-sorted node permutation (kills wave divergence in gathers) ----
    dhist_kernel<<<NBLK, 256, 0, stream>>>(deg, dhist, N);
    dscan_kernel<<<1, NDEGC, 0, stream>>>(dhist, dcur);
    dplace_kernel<<<NBLK, 256, 0, stream>>>(deg, dcur, perm, N);

    // ---- layer 1: fused prescale+agg (x fp32 in) -> matmul -> fp16 A ----
    agg8_kernel<<<(N * 2 + 255) / 256, 256, 0, stream>>>(x, roff, deg, dinv, csrc, perm,
                                                         (float2*)T, N);
    matmul_kernel<8, 16, true><<<(N + 255) / 256, 256, 0, stream>>>(
        (const float4*)T, W1, b1, a1, dinv, (float2*)A, N);

    // ---- layer 2 ----
    agg_h_kernel<16><<<(N * 2 + 255) / 256, 256, 0, stream>>>(
        (const float4*)A, roff, deg, dinv, csrc, perm, (float4*)T, N);
    matmul_kernel<16, 32, true><<<(N + 127) / 128, 256, 0, stream>>>(
        (const float4*)T, W2, b2, a2, dinv, (float2*)A, N);

    // ---- layer 3: agg -> matmul_z ----
    agg_h_kernel<32><<<(N * 4 + 255) / 256, 256, 0, stream>>>(
        (const float4*)A, roff, deg, dinv, csrc, perm, (float4*)T, N);
    matmul_z_kernel<<<(N + 63) / 64, 256, 0, stream>>>(
        (const float4*)T, W3, b3, a3, dinv, M, z, N);

    // ---- layer 4 in z-space: gather-aggregate + pool (original node order) ----
    aggpool4_kernel<<<(N + 255) / 256, 256, 0, stream>>>(
        z, roff, deg, dinv, csrc, batch, pool, cnt, N);
    head_kernel<<<1, 256, 0, stream>>>(pool, cnt, bb, out);
}

// Round 16
// 265.326 us; speedup vs baseline: 1.1358x; 1.1358x over previous
//
#include <hip/hip_runtime.h>
#include <hip/hip_fp16.h>

// Problem constants (match reference file)
#define NN 100000
#define NE 1600000
#define NG 64

// dst-bucketing for the CSR build
#define BSHIFT 7
#define BUCKW (1 << BSHIFT)                 // 128 nodes per bucket
#define NBUCK ((NN + BUCKW - 1) >> BSHIFT)  // 782
#define BIN_CHUNK 8192

// ---- fp16 8-wide helpers (activations stored fp16, math in fp32) ----
union H8 { float4 f4; __half2 h2[4]; };
__device__ __forceinline__ void h8_to_f(const H8& h, float* f) {
    float2 a = __half22float2(h.h2[0]);
    float2 b = __half22float2(h.h2[1]);
    float2 c = __half22float2(h.h2[2]);
    float2 d = __half22float2(h.h2[3]);
    f[0]=a.x; f[1]=a.y; f[2]=b.x; f[3]=b.y; f[4]=c.x; f[5]=c.y; f[6]=d.x; f[7]=d.y;
}
__device__ __forceinline__ H8 f_to_h8(const float* f) {
    H8 h;
    h.h2[0] = __floats2half2_rn(f[0], f[1]);
    h.h2[1] = __floats2half2_rn(f[2], f[3]);
    h.h2[2] = __floats2half2_rn(f[4], f[5]);
    h.h2[3] = __floats2half2_rn(f[6], f[7]);
    return h;
}

// ---------------- bucket histogram (LDS-aggregated) ----------------
__global__ __launch_bounds__(256) void bucket_hist_kernel(const int* __restrict__ dst,
                                                          int* __restrict__ bucket_cnt, int E) {
    __shared__ int h[NBUCK];
    for (int i = threadIdx.x; i < NBUCK; i += 256) h[i] = 0;
    __syncthreads();
    int stride = gridDim.x * 256;
    for (int e = blockIdx.x * 256 + threadIdx.x; e < E; e += stride)
        atomicAdd(&h[dst[e] >> BSHIFT], 1);
    __syncthreads();
    for (int i = threadIdx.x; i < NBUCK; i += 256)
        if (h[i]) atomicAdd(&bucket_cnt[i], h[i]);
}

// ---------------- bucket scan: single block ----------------
__global__ void bucket_scan_kernel(const int* __restrict__ bcnt, int* __restrict__ boff,
                                   int* __restrict__ bcur) {
    __shared__ int buf[2][1024];
    int t = threadIdx.x;
    int v = (t < NBUCK) ? bcnt[t] : 0;
    buf[0][t] = v;
    __syncthreads();
    int cur = 0;
    for (int off = 1; off < 1024; off <<= 1) {
        int x = buf[cur][t];
        if (t >= off) x += buf[cur][t - off];
        buf[cur ^ 1][t] = x;
        __syncthreads();
        cur ^= 1;
    }
    if (t < NBUCK) {
        int e = buf[cur][t] - v;
        boff[t] = e;
        bcur[t] = e;
    }
}

// ---------------- bin edges by dst-bucket; packed (src<<7)|dst_low ----------------
__global__ __launch_bounds__(256) void bin_kernel(const int* __restrict__ src,
                                                  const int* __restrict__ dst,
                                                  int* __restrict__ bcur,
                                                  unsigned* __restrict__ binned, int E) {
    __shared__ int h[NBUCK];
    __shared__ int cur[NBUCK];
    for (int i = threadIdx.x; i < NBUCK; i += 256) h[i] = 0;
    __syncthreads();
    int base = blockIdx.x * BIN_CHUNK;
    int end = base + BIN_CHUNK; if (end > E) end = E;
    for (int e = base + threadIdx.x; e < end; e += 256)
        atomicAdd(&h[dst[e] >> BSHIFT], 1);
    __syncthreads();
    for (int i = threadIdx.x; i < NBUCK; i += 256) {
        int c = h[i];
        cur[i] = c ? atomicAdd(&bcur[i], c) : 0;   // reserve contiguous sub-range
    }
    __syncthreads();
    for (int e = base + threadIdx.x; e < end; e += 256) {
        unsigned s = (unsigned)src[e], d = (unsigned)dst[e];
        int pos = atomicAdd(&cur[d >> BSHIFT], 1);
        binned[pos] = (s << BSHIFT) | (d & (BUCKW - 1));
    }
}

// ---------------- degree + dinv from binned edges ----------------
__global__ __launch_bounds__(256) void deg_dinv_kernel(const unsigned* __restrict__ binned,
                                                       const int* __restrict__ bucket_off,
                                                       const int* __restrict__ bucket_cnt,
                                                       int* __restrict__ deg,
                                                       float* __restrict__ dinv, int n) {
    __shared__ int ldeg[BUCKW];
    int b = blockIdx.x;
    for (int i = threadIdx.x; i < BUCKW; i += 256) ldeg[i] = 0;
    __syncthreads();
    int start = bucket_off[b], cnt = bucket_cnt[b];
    for (int k = threadIdx.x; k < cnt; k += 256)
        atomicAdd(&ldeg[binned[start + k] & (BUCKW - 1)], 1);
    __syncthreads();
    int v0 = b << BSHIFT;
    for (int i = threadIdx.x; i < BUCKW; i += 256) {
        int v = v0 + i;
        if (v < n) {
            int dg = ldeg[i];
            deg[v] = dg;
            dinv[v] = rsqrtf((float)dg + 1.0f);   // +1 = self loop
        }
    }
}

// ---------------- node scan (3 phases) ----------------
__global__ void scan1_kernel(const int* __restrict__ cntin, int* __restrict__ excl,
                             int* __restrict__ bsum, int n) {
    __shared__ int buf[2][1024];
    int t = threadIdx.x;
    int gid = blockIdx.x * 1024 + t;
    int v = (gid < n) ? cntin[gid] : 0;
    buf[0][t] = v;
    __syncthreads();
    int cur = 0;
    for (int off = 1; off < 1024; off <<= 1) {
        int x = buf[cur][t];
        if (t >= off) x += buf[cur][t - off];
        buf[cur ^ 1][t] = x;
        __syncthreads();
        cur ^= 1;
    }
    int incl = buf[cur][t];
    if (gid < n) excl[gid] = incl - v;
    if (t == 1023) bsum[blockIdx.x] = incl;
}

__global__ void scan2_kernel(int* __restrict__ bsum, int nb) {
    __shared__ int buf[2][128];
    int t = threadIdx.x;
    int v = (t < nb) ? bsum[t] : 0;
    buf[0][t] = v;
    __syncthreads();
    int cur = 0;
    for (int off = 1; off < 128; off <<= 1) {
        int x = buf[cur][t];
        if (t >= off) x += buf[cur][t - off];
        buf[cur ^ 1][t] = x;
        __syncthreads();
        cur ^= 1;
    }
    if (t < nb) bsum[t] = buf[cur][t] - v;
}

__global__ void scan3_kernel(int* __restrict__ excl, const int* __restrict__ bsum, int n) {
    int gid = blockIdx.x * blockDim.x + threadIdx.x;
    if (gid < n) excl[gid] += bsum[gid >> 10];
}

// ---------------- final CSR placement ----------------
__global__ __launch_bounds__(256) void build2_kernel(const unsigned* __restrict__ binned,
                                                     const int* __restrict__ bucket_off,
                                                     const int* __restrict__ bucket_cnt,
                                                     const int* __restrict__ roff,
                                                     int* __restrict__ csr_src, int n) {
    __shared__ int lcur[BUCKW];
    int b = blockIdx.x;
    int v0 = b << BSHIFT;
    for (int i = threadIdx.x; i < BUCKW; i += 256) {
        int v = v0 + i;
        lcur[i] = (v < n) ? roff[v] : 0;
    }
    __syncthreads();
    int start = bucket_off[b], cnt = bucket_cnt[b];
    for (int k = threadIdx.x; k < cnt; k += 256) {
        unsigned e = binned[start + k];
        int pos = atomicAdd(&lcur[e & (BUCKW - 1)], 1);
        csr_src[pos] = (int)(e >> BSHIFT);
    }
}

// ---------------- layer-1 aggregation fused with prescale: fp32 x in, fp16 out --------
// T[v] = dinv[v] * (dinv[v]*x[v] + sum_in dinv[s]*x[s]);  G=2 threads/node (float4 each)
__global__ void agg8_kernel(const float* __restrict__ x, const int* __restrict__ row_off,
                            const int* __restrict__ deg, const float* __restrict__ dinv,
                            const int* __restrict__ csr_src, float2* __restrict__ out, int n) {
    int idx = blockIdx.x * blockDim.x + threadIdx.x;
    if (idx >= n * 2) return;
    int v = idx >> 1;
    int c = idx & 1;
    const float4* h4 = (const float4*)x;
    float dvv = dinv[v];
    float4 self = h4[(size_t)v * 2 + c];
    float4 acc = make_float4(self.x * dvv, self.y * dvv, self.z * dvv, self.w * dvv);
    int start = row_off[v], cnt = deg[v];
    const int* __restrict__ row = csr_src + start;
    int j = 0;
    for (; j + 4 <= cnt; j += 4) {
        int s0 = row[j], s1 = row[j + 1], s2 = row[j + 2], s3 = row[j + 3];
        float d0 = dinv[s0], d1 = dinv[s1], d2 = dinv[s2], d3 = dinv[s3];
        float4 a0 = h4[(size_t)s0 * 2 + c];
        float4 a1 = h4[(size_t)s1 * 2 + c];
        float4 a2 = h4[(size_t)s2 * 2 + c];
        float4 a3 = h4[(size_t)s3 * 2 + c];
        acc.x += (a0.x * d0 + a1.x * d1) + (a2.x * d2 + a3.x * d3);
        acc.y += (a0.y * d0 + a1.y * d1) + (a2.y * d2 + a3.y * d3);
        acc.z += (a0.z * d0 + a1.z * d1) + (a2.z * d2 + a3.z * d3);
        acc.w += (a0.w * d0 + a1.w * d1) + (a2.w * d2 + a3.w * d3);
    }
    for (; j < cnt; ++j) {
        int s = row[j];
        float ds = dinv[s];
        float4 a = h4[(size_t)s * 2 + c];
        acc.x += a.x * ds; acc.y += a.y * ds; acc.z += a.z * ds; acc.w += a.w * ds;
    }
    union { float2 f2; __half2 h2[2]; } u;
    u.h2[0] = __floats2half2_rn(acc.x * dvv, acc.y * dvv);
    u.h2[1] = __floats2half2_rn(acc.z * dvv, acc.w * dvv);
    out[idx] = u.f2;        // row = 8 halfs = 2 float2 units
}

// ---------------- fp16 aggregation: out[v] = dinv[v]*(hs[v] + sum_in hs[src]) -----------
template<int FIN>
__global__ void agg_h_kernel(const float4* __restrict__ hs, const int* __restrict__ row_off,
                             const int* __restrict__ deg, const float* __restrict__ dinv,
                             const int* __restrict__ csr_src, float4* __restrict__ out, int n) {
    constexpr int G = FIN / 8;
    int idx = blockIdx.x * blockDim.x + threadIdx.x;
    if (idx >= n * G) return;
    int v = idx / G;
    int c = idx % G;
    float a[8];
    { H8 h; h.f4 = hs[(size_t)v * G + c]; h8_to_f(h, a); }
    int start = row_off[v], cnt = deg[v];
    const int* __restrict__ row = csr_src + start;
    int j = 0;
    for (; j + 8 <= cnt; j += 8) {
        H8 hh[8];
#pragma unroll
        for (int q = 0; q < 8; ++q) hh[q].f4 = hs[(size_t)row[j + q] * G + c];
#pragma unroll
        for (int q = 0; q < 8; ++q) {
            float f[8]; h8_to_f(hh[q], f);
#pragma unroll
            for (int k = 0; k < 8; ++k) a[k] += f[k];
        }
    }
    for (; j + 4 <= cnt; j += 4) {
        H8 h0, h1, h2, h3;
        h0.f4 = hs[(size_t)row[j] * G + c];
        h1.f4 = hs[(size_t)row[j + 1] * G + c];
        h2.f4 = hs[(size_t)row[j + 2] * G + c];
        h3.f4 = hs[(size_t)row[j + 3] * G + c];
        float f0[8], f1[8], f2[8], f3[8];
        h8_to_f(h0, f0); h8_to_f(h1, f1); h8_to_f(h2, f2); h8_to_f(h3, f3);
#pragma unroll
        for (int k = 0; k < 8; ++k) a[k] += (f0[k] + f1[k]) + (f2[k] + f3[k]);
    }
    for (; j < cnt; ++j) {
        H8 h; h.f4 = hs[(size_t)row[j] * G + c];
        float f[8]; h8_to_f(h, f);
#pragma unroll
        for (int k = 0; k < 8; ++k) a[k] += f[k];
    }
    float dv = dinv[v];
#pragma unroll
    for (int k = 0; k < 8; ++k) a[k] *= dv;
    H8 o = f_to_h8(a);
    out[(size_t)v * G + c] = o.f4;
}

// ---------------- fused matmul + bias + prelu; fp16 in/out, fp32 math ----------------
template<int FIN, int FOUT, bool SCALE>
__global__ __launch_bounds__(256) void matmul_kernel(
    const float4* __restrict__ tin, const float* __restrict__ W,
    const float* __restrict__ bias, const float* __restrict__ slope,
    const float* __restrict__ dinv, float2* __restrict__ hout, int n) {
    constexpr int TPN = FOUT / 4;            // threads per node (4 outputs each)
    constexpr int NPB = (256 / TPN) * 4;     // nodes per block
    __shared__ float4 Wl[FIN * TPN];
    const float4* Wg = (const float4*)W;
    for (int i = threadIdx.x; i < FIN * TPN; i += 256) Wl[i] = Wg[i];
    __syncthreads();
    int t = threadIdx.x;
    int grp = t / TPN;
    int f4 = t % TPN;
    int v0 = blockIdx.x * NPB + grp * 4;
    float s = slope ? *slope : 1.0f;
    float4 bv = ((const float4*)bias)[f4];
    float4 acc[4];
#pragma unroll
    for (int nn = 0; nn < 4; ++nn) acc[nn] = bv;
#pragma unroll
    for (int i = 0; i < FIN; i += 8) {
        float r[4][8];
#pragma unroll
        for (int nn = 0; nn < 4; ++nn) {
            int v = v0 + nn;
            H8 h;
            h.f4 = (v < n) ? tin[(size_t)v * (FIN / 8) + (i >> 3)]
                           : make_float4(0.f, 0.f, 0.f, 0.f);
            h8_to_f(h, r[nn]);
        }
#pragma unroll
        for (int k = 0; k < 8; ++k) {
            float4 wv = Wl[(i + k) * TPN + f4];
#pragma unroll
            for (int nn = 0; nn < 4; ++nn) {
                float rk = r[nn][k];
                acc[nn].x += wv.x * rk;
                acc[nn].y += wv.y * rk;
                acc[nn].z += wv.z * rk;
                acc[nn].w += wv.w * rk;
            }
        }
    }
#pragma unroll
    for (int nn = 0; nn < 4; ++nn) {
        int v = v0 + nn;
        if (v < n) {
            float m = SCALE ? dinv[v] : 1.0f;
            float ox = (fmaxf(acc[nn].x, 0.f) + s * fminf(acc[nn].x, 0.f)) * m;
            float oy = (fmaxf(acc[nn].y, 0.f) + s * fminf(acc[nn].y, 0.f)) * m;
            float oz = (fmaxf(acc[nn].z, 0.f) + s * fminf(acc[nn].z, 0.f)) * m;
            float ow = (fmaxf(acc[nn].w, 0.f) + s * fminf(acc[nn].w, 0.f)) * m;
            union { float2 f2; __half2 h2[2]; } u;
            u.h2[0] = __floats2half2_rn(ox, oy);
            u.h2[1] = __floats2half2_rn(oz, ow);
            hout[(size_t)v * TPN + f4] = u.f2;   // row = FOUT halfs = TPN float2s
        }
    }
}

// ---------------- makeM: M = W4 @ Wlin (64x4), bb = b4 @ Wlin + blin ----------------
__global__ __launch_bounds__(256) void makeM_kernel(
    const float* __restrict__ W4, const float* __restrict__ b4,
    const float* __restrict__ Wlin, const float* __restrict__ blin,
    float* __restrict__ M, float* __restrict__ bb) {
    int t = threadIdx.x;          // 256 = 64 * 4
    int k = t >> 2, c = t & 3;
    float m = 0.f;
    for (int j = 0; j < 128; ++j) m += W4[k * 128 + j] * Wlin[j * 4 + c];
    M[k * 4 + c] = m;
    if (t < 4) {
        float v = blin[t];
        for (int j = 0; j < 128; ++j) v += b4[j] * Wlin[j * 4 + t];
        bb[t] = v;
    }
}

// ---------------- layer-3 matmul fused with z-projection (shuffle-reduced) ------------
__global__ __launch_bounds__(256) void matmul_z_kernel(
    const float4* __restrict__ tin, const float* __restrict__ W,
    const float* __restrict__ bias, const float* __restrict__ slope,
    const float* __restrict__ dinv, const float* __restrict__ M,
    float4* __restrict__ z, int n) {
    constexpr int FIN = 32, FOUT = 64, TPN = FOUT / 4, NPB = 64;
    __shared__ float4 Wl[FIN * TPN];           // 8 KB
    __shared__ float4 Ml[FOUT];                // 1 KB  (row f -> M[f][0..3])
    const float4* Wg = (const float4*)W;
    for (int i = threadIdx.x; i < FIN * TPN; i += 256) Wl[i] = Wg[i];
    if (threadIdx.x < FOUT) Ml[threadIdx.x] = ((const float4*)M)[threadIdx.x];
    __syncthreads();
    int t = threadIdx.x;
    int grp = t / TPN;
    int f4 = t % TPN;
    int v0 = blockIdx.x * NPB + grp * 4;
    float s = *slope;
    float4 bv = ((const float4*)bias)[f4];
    float4 acc[4];
#pragma unroll
    for (int nn = 0; nn < 4; ++nn) acc[nn] = bv;
#pragma unroll
    for (int i = 0; i < FIN; i += 8) {
        float r[4][8];
#pragma unroll
        for (int nn = 0; nn < 4; ++nn) {
            int v = v0 + nn;
            H8 h;
            h.f4 = (v < n) ? tin[(size_t)v * (FIN / 8) + (i >> 3)]
                           : make_float4(0.f, 0.f, 0.f, 0.f);
            h8_to_f(h, r[nn]);
        }
#pragma unroll
        for (int k = 0; k < 8; ++k) {
            float4 wv = Wl[(i + k) * TPN + f4];
#pragma unroll
            for (int nn = 0; nn < 4; ++nn) {
                float rk = r[nn][k];
                acc[nn].x += wv.x * rk;
                acc[nn].y += wv.y * rk;
                acc[nn].z += wv.z * rk;
                acc[nn].w += wv.w * rk;
            }
        }
    }
    float4 m0 = Ml[f4 * 4 + 0];
    float4 m1 = Ml[f4 * 4 + 1];
    float4 m2 = Ml[f4 * 4 + 2];
    float4 m3 = Ml[f4 * 4 + 3];
#pragma unroll
    for (int nn = 0; nn < 4; ++nn) {
        int v = v0 + nn;
        float dvm = (v < n) ? dinv[v] : 0.f;
        float ox = (fmaxf(acc[nn].x, 0.f) + s * fminf(acc[nn].x, 0.f)) * dvm;
        float oy = (fmaxf(acc[nn].y, 0.f) + s * fminf(acc[nn].y, 0.f)) * dvm;
        float oz = (fmaxf(acc[nn].z, 0.f) + s * fminf(acc[nn].z, 0.f)) * dvm;
        float ow = (fmaxf(acc[nn].w, 0.f) + s * fminf(acc[nn].w, 0.f)) * dvm;
        float px = ox * m0.x + oy * m1.x + oz * m2.x + ow * m3.x;
        float py = ox * m0.y + oy * m1.y + oz * m2.y + ow * m3.y;
        float pz = ox * m0.z + oy * m1.z + oz * m2.z + ow * m3.z;
        float pw = ox * m0.w + oy * m1.w + oz * m2.w + ow * m3.w;
#pragma unroll
        for (int mask = 8; mask >= 1; mask >>= 1) {
            px += __shfl_xor(px, mask, 16);
            py += __shfl_xor(py, mask, 16);
            pz += __shfl_xor(pz, mask, 16);
            pw += __shfl_xor(pw, mask, 16);
        }
        if (f4 == 0 && v < n) z[v] = make_float4(px, py, pz, pw);
    }
}

// ---------------- layer-4 aggregation + pooling in z-space (wave-reduced) --------------
// batch is sorted, so a 64-lane wave almost always covers one graph: shuffle-reduce the
// 4-component contribution across the wave and issue ONE set of LDS atomics per wave.
__global__ __launch_bounds__(256) void aggpool4_kernel(
    const float4* __restrict__ z, const int* __restrict__ row_off,
    const int* __restrict__ deg, const float* __restrict__ dinv,
    const int* __restrict__ csr_src, const int* __restrict__ batch,
    float* __restrict__ sums, float* __restrict__ cnt, int n) {
    __shared__ float lacc[NG * 4];
    __shared__ float lcnt[NG];
    int tid = threadIdx.x;
    if (tid < NG * 4) lacc[tid] = 0.f;
    if (tid < NG) lcnt[tid] = 0.f;
    __syncthreads();
    int v = blockIdx.x * 256 + tid;
    bool valid = (v < n);
    float cx = 0.f, cy = 0.f, cz = 0.f, cw = 0.f, rc = 0.f;
    int g = -1;
    if (valid) {
        float4 acc = z[v];
        int start = row_off[v], dcnt = deg[v];
        const int* __restrict__ row = csr_src + start;
        int j = 0;
        for (; j + 4 <= dcnt; j += 4) {
            float4 a0 = z[row[j]];
            float4 a1 = z[row[j + 1]];
            float4 a2 = z[row[j + 2]];
            float4 a3 = z[row[j + 3]];
            acc.x += (a0.x + a1.x) + (a2.x + a3.x);
            acc.y += (a0.y + a1.y) + (a2.y + a3.y);
            acc.z += (a0.z + a1.z) + (a2.z + a3.z);
            acc.w += (a0.w + a1.w) + (a2.w + a3.w);
        }
        for (; j < dcnt; ++j) {
            float4 a = z[row[j]];
            acc.x += a.x; acc.y += a.y; acc.z += a.z; acc.w += a.w;
        }
        float dv = dinv[v];
        cx = acc.x * dv; cy = acc.y * dv; cz = acc.z * dv; cw = acc.w * dv;
        rc = 1.f;
        g = batch[v];
    }
    int g0 = __shfl(g, 0, 64);           // lane 0 of each wave is always valid
    if (__all(g == g0 || !valid)) {
        // uniform wave: butterfly reduce, single LDS update by lane 0
#pragma unroll
        for (int mask = 32; mask >= 1; mask >>= 1) {
            cx += __shfl_xor(cx, mask, 64);
            cy += __shfl_xor(cy, mask, 64);
            cz += __shfl_xor(cz, mask, 64);
            cw += __shfl_xor(cw, mask, 64);
            rc += __shfl_xor(rc, mask, 64);
        }
        if ((tid & 63) == 0) {
            float* lp = &lacc[g0 * 4];
            atomicAdd(lp + 0, cx); atomicAdd(lp + 1, cy);
            atomicAdd(lp + 2, cz); atomicAdd(lp + 3, cw);
            atomicAdd(&lcnt[g0], rc);
        }
    } else if (valid) {
        float* lp = &lacc[g * 4];
        atomicAdd(lp + 0, cx); atomicAdd(lp + 1, cy);
        atomicAdd(lp + 2, cz); atomicAdd(lp + 3, cw);
        atomicAdd(&lcnt[g], 1.f);
    }
    __syncthreads();
    if (tid < NG * 4) {
        float val = lacc[tid];
        if (val != 0.f) atomicAdd(&sums[tid], val);
    }
    if (tid < NG) {
        float val = lcnt[tid];
        if (val != 0.f) atomicAdd(&cnt[tid], val);
    }
}

// ---------------- head: out[g][c] = sums[g][c]/cnt[g] + bb[c] ----------------
__global__ void head_kernel(const float* __restrict__ sums, const float* __restrict__ cnt,
                            const float* __restrict__ bb, float* __restrict__ out) {
    int t = threadIdx.x;          // 256 = 64 graphs * 4 classes
    int g = t >> 2, c = t & 3;
    out[t] = sums[t] / fmaxf(cnt[g], 1.f) + bb[c];
}

extern "C" void kernel_launch(void* const* d_in, const int* in_sizes, int n_in,
                              void* d_out, int out_size, void* d_ws, size_t ws_size,
                              hipStream_t stream) {
    const float* x    = (const float*)d_in[0];
    const int* esrc   = (const int*)d_in[1];
    const int* edst   = (const int*)d_in[2];
    const int* batch  = (const int*)d_in[3];
    const float* W1 = (const float*)d_in[4],  *b1 = (const float*)d_in[5];
    const float* W2 = (const float*)d_in[6],  *b2 = (const float*)d_in[7];
    const float* W3 = (const float*)d_in[8],  *b3 = (const float*)d_in[9];
    const float* W4 = (const float*)d_in[10], *b4 = (const float*)d_in[11];
    const float* a1 = (const float*)d_in[12];
    const float* a2 = (const float*)d_in[13];
    const float* a3 = (const float*)d_in[14];
    const float* Wlin = (const float*)d_in[15], *blin = (const float*)d_in[16];
    float* out = (float*)d_out;

    const int N = NN, E = NE;
    const int NB = (N + 1023) / 1024;                   // node-scan blocks (98)
    const int NBIN = (E + BIN_CHUNK - 1) / BIN_CHUNK;   // 196

    // workspace carve-up
    char* w = (char*)d_ws;
    size_t off = 0;
    auto alloc = [&](size_t bytes) { size_t r = off; off += (bytes + 255) & ~(size_t)255; return r; };
    size_t o_bcnt = alloc((size_t)NBUCK * 4);      // needs zero
    size_t o_pool = alloc((size_t)NG * 4 * 4);     // needs zero (pooled z sums)
    size_t o_cnt  = alloc((size_t)NG * 4);         // needs zero
    size_t zero_bytes = off;
    size_t o_deg  = alloc((size_t)N * 4);
    size_t o_dinv = alloc((size_t)N * 4);
    size_t o_roff = alloc((size_t)N * 4);
    size_t o_boff = alloc((size_t)NBUCK * 4);
    size_t o_bcur = alloc((size_t)NBUCK * 4);
    size_t o_bsum = alloc((size_t)128 * 4);
    size_t o_csrc = alloc((size_t)E * 4);
    size_t o_bin  = alloc((size_t)E * 4);          // packed (src<<7)|dst_low
    size_t o_A    = alloc((size_t)N * 32 * 2);     // activations fp16 (max 32 halfs)
    size_t o_T    = alloc((size_t)N * 32 * 2);     // agg output fp16 (max 32 halfs)
    size_t o_z    = alloc((size_t)N * 4 * 4);      // z projections (float4/node)
    size_t o_M    = alloc((size_t)64 * 4 * 4);     // W4@Wlin
    size_t o_bb   = alloc((size_t)4 * 4);          // b4@Wlin + blin
    (void)ws_size;
    int*      bcnt   = (int*)(w + o_bcnt);
    float*    pool   = (float*)(w + o_pool);
    float*    cnt    = (float*)(w + o_cnt);
    int*      deg    = (int*)(w + o_deg);
    float*    dinv   = (float*)(w + o_dinv);
    int*      roff   = (int*)(w + o_roff);
    int*      boff   = (int*)(w + o_boff);
    int*      bcur   = (int*)(w + o_bcur);
    int*      bsum   = (int*)(w + o_bsum);
    int*      csrc   = (int*)(w + o_csrc);
    unsigned* binned = (unsigned*)(w + o_bin);
    char*     A      = (char*)(w + o_A);
    char*     T      = (char*)(w + o_T);
    float4*   z      = (float4*)(w + o_z);
    float*    M      = (float*)(w + o_M);
    float*    bb     = (float*)(w + o_bb);

    hipMemsetAsync(w, 0, zero_bytes, stream);

    // ---- head constants (independent; launch early) ----
    makeM_kernel<<<1, 256, 0, stream>>>(W4, b4, Wlin, blin, M, bb);

    // ---- CSR build via dst-bucket binning (once, reused by all 4 layers) ----
    bucket_hist_kernel<<<256, 256, 0, stream>>>(edst, bcnt, E);
    bucket_scan_kernel<<<1, 1024, 0, stream>>>(bcnt, boff, bcur);
    bin_kernel<<<NBIN, 256, 0, stream>>>(esrc, edst, bcur, binned, E);
    deg_dinv_kernel<<<NBUCK, 256, 0, stream>>>(binned, boff, bcnt, deg, dinv, N);
    scan1_kernel<<<NB, 1024, 0, stream>>>(deg, roff, bsum, N);
    scan2_kernel<<<1, 128, 0, stream>>>(bsum, NB);
    scan3_kernel<<<(N + 255) / 256, 256, 0, stream>>>(roff, bsum, N);
    build2_kernel<<<NBUCK, 256, 0, stream>>>(binned, boff, bcnt, roff, csrc, N);

    // ---- layer 1: fused prescale+agg (x fp32 in) -> matmul -> fp16 A ----
    agg8_kernel<<<(N * 2 + 255) / 256, 256, 0, stream>>>(x, roff, deg, dinv, csrc, (float2*)T, N);
    matmul_kernel<8, 16, true><<<(N + 255) / 256, 256, 0, stream>>>(
        (const float4*)T, W1, b1, a1, dinv, (float2*)A, N);

    // ---- layer 2 ----
    agg_h_kernel<16><<<(N * 2 + 255) / 256, 256, 0, stream>>>(
        (const float4*)A, roff, deg, dinv, csrc, (float4*)T, N);
    matmul_kernel<16, 32, true><<<(N + 127) / 128, 256, 0, stream>>>(
        (const float4*)T, W2, b2, a2, dinv, (float2*)A, N);

    // ---- layer 3: agg -> matmul_z (z = dinv*prelu(row) @ M; A never materialized) ----
    agg_h_kernel<32><<<(N * 4 + 255) / 256, 256, 0, stream>>>(
        (const float4*)A, roff, deg, dinv, csrc, (float4*)T, N);
    matmul_z_kernel<<<(N + 63) / 64, 256, 0, stream>>>(
        (const float4*)T, W3, b3, a3, dinv, M, z, N);

    // ---- layer 4 in z-space: gather-aggregate + pool over N x 4 (L2-resident) ----
    aggpool4_kernel<<<(N + 255) / 256, 256, 0, stream>>>(
        z, roff, deg, dinv, csrc, batch, pool, cnt, N);
    head_kernel<<<1, 256, 0, stream>>>(pool, cnt, bb, out);
}

// Round 17
// 258.291 us; speedup vs baseline: 1.1667x; 1.0272x over previous
//
#include <hip/hip_runtime.h>
#include <hip/hip_fp16.h>

// Problem constants (match reference file)
#define NN 100000
#define NE 1600000
#define NG 64

// dst-bucketing for the CSR build
#define BSHIFT 7
#define BUCKW (1 << BSHIFT)                 // 128 nodes per bucket
#define NBUCK ((NN + BUCKW - 1) >> BSHIFT)  // 782
#define BIN_CHUNK 8192

// ---- fp16 8-wide helpers (activations stored fp16, math in fp32) ----
union H8 { float4 f4; __half2 h2[4]; };
__device__ __forceinline__ void h8_to_f(const H8& h, float* f) {
    float2 a = __half22float2(h.h2[0]);
    float2 b = __half22float2(h.h2[1]);
    float2 c = __half22float2(h.h2[2]);
    float2 d = __half22float2(h.h2[3]);
    f[0]=a.x; f[1]=a.y; f[2]=b.x; f[3]=b.y; f[4]=c.x; f[5]=c.y; f[6]=d.x; f[7]=d.y;
}
__device__ __forceinline__ H8 f_to_h8(const float* f) {
    H8 h;
    h.h2[0] = __floats2half2_rn(f[0], f[1]);
    h.h2[1] = __floats2half2_rn(f[2], f[3]);
    h.h2[2] = __floats2half2_rn(f[4], f[5]);
    h.h2[3] = __floats2half2_rn(f[6], f[7]);
    return h;
}
__device__ __forceinline__ float prelu_f(float x, float s) {
    return fmaxf(x, 0.f) + s * fminf(x, 0.f);
}

// ---------------- bucket histogram (LDS-aggregated) ----------------
__global__ __launch_bounds__(256) void bucket_hist_kernel(const int* __restrict__ dst,
                                                          int* __restrict__ bucket_cnt, int E) {
    __shared__ int h[NBUCK];
    for (int i = threadIdx.x; i < NBUCK; i += 256) h[i] = 0;
    __syncthreads();
    int stride = gridDim.x * 256;
    for (int e = blockIdx.x * 256 + threadIdx.x; e < E; e += stride)
        atomicAdd(&h[dst[e] >> BSHIFT], 1);
    __syncthreads();
    for (int i = threadIdx.x; i < NBUCK; i += 256)
        if (h[i]) atomicAdd(&bucket_cnt[i], h[i]);
}

// ---------------- bucket scan: single block ----------------
__global__ void bucket_scan_kernel(const int* __restrict__ bcnt, int* __restrict__ boff,
                                   int* __restrict__ bcur) {
    __shared__ int buf[2][1024];
    int t = threadIdx.x;
    int v = (t < NBUCK) ? bcnt[t] : 0;
    buf[0][t] = v;
    __syncthreads();
    int cur = 0;
    for (int off = 1; off < 1024; off <<= 1) {
        int x = buf[cur][t];
        if (t >= off) x += buf[cur][t - off];
        buf[cur ^ 1][t] = x;
        __syncthreads();
        cur ^= 1;
    }
    if (t < NBUCK) {
        int e = buf[cur][t] - v;
        boff[t] = e;
        bcur[t] = e;
    }
}

// ---------------- bin edges by dst-bucket; packed (src<<7)|dst_low ----------------
__global__ __launch_bounds__(256) void bin_kernel(const int* __restrict__ src,
                                                  const int* __restrict__ dst,
                                                  int* __restrict__ bcur,
                                                  unsigned* __restrict__ binned, int E) {
    __shared__ int h[NBUCK];
    __shared__ int cur[NBUCK];
    for (int i = threadIdx.x; i < NBUCK; i += 256) h[i] = 0;
    __syncthreads();
    int base = blockIdx.x * BIN_CHUNK;
    int end = base + BIN_CHUNK; if (end > E) end = E;
    for (int e = base + threadIdx.x; e < end; e += 256)
        atomicAdd(&h[dst[e] >> BSHIFT], 1);
    __syncthreads();
    for (int i = threadIdx.x; i < NBUCK; i += 256) {
        int c = h[i];
        cur[i] = c ? atomicAdd(&bcur[i], c) : 0;   // reserve contiguous sub-range
    }
    __syncthreads();
    for (int e = base + threadIdx.x; e < end; e += 256) {
        unsigned s = (unsigned)src[e], d = (unsigned)dst[e];
        int pos = atomicAdd(&cur[d >> BSHIFT], 1);
        binned[pos] = (s << BSHIFT) | (d & (BUCKW - 1));
    }
}

// ---------------- degree + dinv from binned edges ----------------
__global__ __launch_bounds__(256) void deg_dinv_kernel(const unsigned* __restrict__ binned,
                                                       const int* __restrict__ bucket_off,
                                                       const int* __restrict__ bucket_cnt,
                                                       int* __restrict__ deg,
                                                       float* __restrict__ dinv, int n) {
    __shared__ int ldeg[BUCKW];
    int b = blockIdx.x;
    for (int i = threadIdx.x; i < BUCKW; i += 256) ldeg[i] = 0;
    __syncthreads();
    int start = bucket_off[b], cnt = bucket_cnt[b];
    for (int k = threadIdx.x; k < cnt; k += 256)
        atomicAdd(&ldeg[binned[start + k] & (BUCKW - 1)], 1);
    __syncthreads();
    int v0 = b << BSHIFT;
    for (int i = threadIdx.x; i < BUCKW; i += 256) {
        int v = v0 + i;
        if (v < n) {
            int dg = ldeg[i];
            deg[v] = dg;
            dinv[v] = rsqrtf((float)dg + 1.0f);   // +1 = self loop
        }
    }
}

// ---------------- node scan (3 phases) ----------------
__global__ void scan1_kernel(const int* __restrict__ cntin, int* __restrict__ excl,
                             int* __restrict__ bsum, int n) {
    __shared__ int buf[2][1024];
    int t = threadIdx.x;
    int gid = blockIdx.x * 1024 + t;
    int v = (gid < n) ? cntin[gid] : 0;
    buf[0][t] = v;
    __syncthreads();
    int cur = 0;
    for (int off = 1; off < 1024; off <<= 1) {
        int x = buf[cur][t];
        if (t >= off) x += buf[cur][t - off];
        buf[cur ^ 1][t] = x;
        __syncthreads();
        cur ^= 1;
    }
    int incl = buf[cur][t];
    if (gid < n) excl[gid] = incl - v;
    if (t == 1023) bsum[blockIdx.x] = incl;
}

__global__ void scan2_kernel(int* __restrict__ bsum, int nb) {
    __shared__ int buf[2][128];
    int t = threadIdx.x;
    int v = (t < nb) ? bsum[t] : 0;
    buf[0][t] = v;
    __syncthreads();
    int cur = 0;
    for (int off = 1; off < 128; off <<= 1) {
        int x = buf[cur][t];
        if (t >= off) x += buf[cur][t - off];
        buf[cur ^ 1][t] = x;
        __syncthreads();
        cur ^= 1;
    }
    if (t < nb) bsum[t] = buf[cur][t] - v;
}

__global__ void scan3_kernel(int* __restrict__ excl, const int* __restrict__ bsum, int n) {
    int gid = blockIdx.x * blockDim.x + threadIdx.x;
    if (gid < n) excl[gid] += bsum[gid >> 10];
}

// ---------------- final CSR placement ----------------
__global__ __launch_bounds__(256) void build2_kernel(const unsigned* __restrict__ binned,
                                                     const int* __restrict__ bucket_off,
                                                     const int* __restrict__ bucket_cnt,
                                                     const int* __restrict__ roff,
                                                     int* __restrict__ csr_src, int n) {
    __shared__ int lcur[BUCKW];
    int b = blockIdx.x;
    int v0 = b << BSHIFT;
    for (int i = threadIdx.x; i < BUCKW; i += 256) {
        int v = v0 + i;
        lcur[i] = (v < n) ? roff[v] : 0;
    }
    __syncthreads();
    int start = bucket_off[b], cnt = bucket_cnt[b];
    for (int k = threadIdx.x; k < cnt; k += 256) {
        unsigned e = binned[start + k];
        int pos = atomicAdd(&lcur[e & (BUCKW - 1)], 1);
        csr_src[pos] = (int)(e >> BSHIFT);
    }
}

// ---------------- makeM: M = W4 @ Wlin (64x4), bb = b4 @ Wlin + blin ----------------
__global__ __launch_bounds__(256) void makeM_kernel(
    const float* __restrict__ W4, const float* __restrict__ b4,
    const float* __restrict__ Wlin, const float* __restrict__ blin,
    float* __restrict__ M, float* __restrict__ bb) {
    int t = threadIdx.x;          // 256 = 64 * 4
    int k = t >> 2, c = t & 3;
    float m = 0.f;
    for (int j = 0; j < 128; ++j) m += W4[k * 128 + j] * Wlin[j * 4 + c];
    M[k * 4 + c] = m;
    if (t < 4) {
        float v = blin[t];
        for (int j = 0; j < 128; ++j) v += b4[j] * Wlin[j * 4 + t];
        bb[t] = v;
    }
}

// ======== LAYER 1 fused: prescale + agg(8) + matmul(8->16) + prelu + dinv-scale ========
// G=2 threads/node; each gathers a float4 half-row, pair-exchanges, computes 8 of 16
// outputs against LDS W1, writes 8 fp16 (one float4).
__global__ __launch_bounds__(256) void aggmm1_kernel(
    const float* __restrict__ x, const int* __restrict__ row_off,
    const int* __restrict__ deg, const float* __restrict__ dinv,
    const int* __restrict__ csr_src, const float* __restrict__ W1,
    const float* __restrict__ b1, const float* __restrict__ a1,
    float4* __restrict__ Aout, int n) {
    __shared__ float Wl[8 * 16];
    for (int i = threadIdx.x; i < 8 * 16; i += 256) Wl[i] = W1[i];
    __syncthreads();
    int idx = blockIdx.x * 256 + threadIdx.x;
    if (idx >= n * 2) return;                 // pairwise-aligned tail: partners agree
    int v = idx >> 1;
    int c = idx & 1;
    const float4* h4 = (const float4*)x;
    float dvv = dinv[v];
    float4 self = h4[(size_t)v * 2 + c];
    float4 acc = make_float4(self.x * dvv, self.y * dvv, self.z * dvv, self.w * dvv);
    int start = row_off[v], cnt = deg[v];
    const int* __restrict__ row = csr_src + start;
    int j = 0;
    for (; j + 4 <= cnt; j += 4) {
        int s0 = row[j], s1 = row[j + 1], s2 = row[j + 2], s3 = row[j + 3];
        float d0 = dinv[s0], d1 = dinv[s1], d2 = dinv[s2], d3 = dinv[s3];
        float4 a0 = h4[(size_t)s0 * 2 + c];
        float4 a1v = h4[(size_t)s1 * 2 + c];
        float4 a2 = h4[(size_t)s2 * 2 + c];
        float4 a3 = h4[(size_t)s3 * 2 + c];
        acc.x += (a0.x * d0 + a1v.x * d1) + (a2.x * d2 + a3.x * d3);
        acc.y += (a0.y * d0 + a1v.y * d1) + (a2.y * d2 + a3.y * d3);
        acc.z += (a0.z * d0 + a1v.z * d1) + (a2.z * d2 + a3.z * d3);
        acc.w += (a0.w * d0 + a1v.w * d1) + (a2.w * d2 + a3.w * d3);
    }
    for (; j < cnt; ++j) {
        int s = row[j];
        float ds = dinv[s];
        float4 a = h4[(size_t)s * 2 + c];
        acc.x += a.x * ds; acc.y += a.y * ds; acc.z += a.z * ds; acc.w += a.w * ds;
    }
    float t[4] = { acc.x * dvv, acc.y * dvv, acc.z * dvv, acc.w * dvv };
    float po[4];
#pragma unroll
    for (int k = 0; k < 4; ++k) po[k] = __shfl_xor(t[k], 1, 64);
    // matmul: own elements at base c*4, partner at (1-c)*4; outputs [c*8, c*8+8)
    int ob = c * 8;
    int e0 = c * 4, e1 = 4 - e0;
    float accm[8];
#pragma unroll
    for (int q = 0; q < 8; ++q) accm[q] = b1[ob + q];
#pragma unroll
    for (int k = 0; k < 4; ++k) {
        float r1 = t[k], r2 = po[k];
        const float* w1 = &Wl[(e0 + k) * 16 + ob];
        const float* w2 = &Wl[(e1 + k) * 16 + ob];
#pragma unroll
        for (int q = 0; q < 8; ++q) accm[q] += r1 * w1[q] + r2 * w2[q];
    }
    float s = *a1;
    float o[8];
#pragma unroll
    for (int q = 0; q < 8; ++q) o[q] = prelu_f(accm[q], s) * dvv;
    H8 h = f_to_h8(o);
    Aout[(size_t)v * 2 + c] = h.f4;   // A-row = 16 halfs = 2 float4s
}

// ======== LAYER 2 fused: agg(16) + matmul(16->32) + prelu + dinv-scale ========
// G=2 threads/node; 8-half gathers, pair-exchange 8 floats, 16 of 32 outputs each.
__global__ __launch_bounds__(256) void aggmm2_kernel(
    const float4* __restrict__ hs, const int* __restrict__ row_off,
    const int* __restrict__ deg, const float* __restrict__ dinv,
    const int* __restrict__ csr_src, const float* __restrict__ W2,
    const float* __restrict__ b2, const float* __restrict__ a2,
    float4* __restrict__ Aout, int n) {
    __shared__ float Wl[16 * 32];   // 2 KB
    for (int i = threadIdx.x; i < 16 * 32; i += 256) Wl[i] = W2[i];
    __syncthreads();
    int idx = blockIdx.x * 256 + threadIdx.x;
    if (idx >= n * 2) return;
    int v = idx >> 1;
    int c = idx & 1;
    float a[8];
    { H8 h; h.f4 = hs[(size_t)v * 2 + c]; h8_to_f(h, a); }
    int start = row_off[v], cnt = deg[v];
    const int* __restrict__ row = csr_src + start;
    int j = 0;
    for (; j + 8 <= cnt; j += 8) {
        H8 hh[8];
#pragma unroll
        for (int q = 0; q < 8; ++q) hh[q].f4 = hs[(size_t)row[j + q] * 2 + c];
#pragma unroll
        for (int q = 0; q < 8; ++q) {
            float f[8]; h8_to_f(hh[q], f);
#pragma unroll
            for (int k = 0; k < 8; ++k) a[k] += f[k];
        }
    }
    for (; j < cnt; ++j) {
        H8 h; h.f4 = hs[(size_t)row[j] * 2 + c];
        float f[8]; h8_to_f(h, f);
#pragma unroll
        for (int k = 0; k < 8; ++k) a[k] += f[k];
    }
    float dvv = dinv[v];
#pragma unroll
    for (int k = 0; k < 8; ++k) a[k] *= dvv;
    float pa[8];
#pragma unroll
    for (int k = 0; k < 8; ++k) pa[k] = __shfl_xor(a[k], 1, 64);
    int ob = c * 16;
    int e0 = c * 8, e1 = 8 - e0;
    float accm[16];
#pragma unroll
    for (int q = 0; q < 16; ++q) accm[q] = b2[ob + q];
#pragma unroll
    for (int k = 0; k < 8; ++k) {
        float r1 = a[k], r2 = pa[k];
        const float* w1 = &Wl[(e0 + k) * 32 + ob];
        const float* w2 = &Wl[(e1 + k) * 32 + ob];
#pragma unroll
        for (int q = 0; q < 16; ++q) accm[q] += r1 * w1[q] + r2 * w2[q];
    }
    float s = *a2;
    float o[16];
#pragma unroll
    for (int q = 0; q < 16; ++q) o[q] = prelu_f(accm[q], s) * dvv;
    H8 h0 = f_to_h8(o);
    H8 h1 = f_to_h8(o + 8);
    Aout[(size_t)v * 4 + c * 2 + 0] = h0.f4;   // A-row = 32 halfs = 4 float4s
    Aout[(size_t)v * 4 + c * 2 + 1] = h1.f4;
}

// ======== LAYER 3 fused: agg(32) + matmul(32->64) + prelu + dinv + @M -> z ========
// G=4 threads/node; quad xor-pass exchange, 16 of 64 outputs each, project through M,
// quad shuffle-reduce, lane 0 writes z[v] (float4).
__global__ __launch_bounds__(256) void aggmm3_kernel(
    const float4* __restrict__ hs, const int* __restrict__ row_off,
    const int* __restrict__ deg, const float* __restrict__ dinv,
    const int* __restrict__ csr_src, const float* __restrict__ W3,
    const float* __restrict__ b3, const float* __restrict__ a3,
    const float* __restrict__ M, float4* __restrict__ z, int n) {
    __shared__ float Wl[32 * 64];   // 8 KB
    __shared__ float Ml[64 * 4];    // 1 KB
    for (int i = threadIdx.x; i < 32 * 64; i += 256) Wl[i] = W3[i];
    if (threadIdx.x < 64 * 4 && threadIdx.x < 256) { /* covered below */ }
    for (int i = threadIdx.x; i < 64 * 4; i += 256) Ml[i] = M[i];
    __syncthreads();
    int idx = blockIdx.x * 256 + threadIdx.x;
    if (idx >= n * 4) return;                 // quad-aligned tail
    int v = idx >> 2;
    int c = idx & 3;
    float a[8];
    { H8 h; h.f4 = hs[(size_t)v * 4 + c]; h8_to_f(h, a); }
    int start = row_off[v], cnt = deg[v];
    const int* __restrict__ row = csr_src + start;
    int j = 0;
    for (; j + 8 <= cnt; j += 8) {
        H8 hh[8];
#pragma unroll
        for (int q = 0; q < 8; ++q) hh[q].f4 = hs[(size_t)row[j + q] * 4 + c];
#pragma unroll
        for (int q = 0; q < 8; ++q) {
            float f[8]; h8_to_f(hh[q], f);
#pragma unroll
            for (int k = 0; k < 8; ++k) a[k] += f[k];
        }
    }
    for (; j < cnt; ++j) {
        H8 h; h.f4 = hs[(size_t)row[j] * 4 + c];
        float f[8]; h8_to_f(h, f);
#pragma unroll
        for (int k = 0; k < 8; ++k) a[k] += f[k];
    }
    float dvv = dinv[v];
#pragma unroll
    for (int k = 0; k < 8; ++k) a[k] *= dvv;
    // matmul over 4 xor-passes (own + 3 partners), outputs [c*16, c*16+16)
    int ob = c * 16;
    float accm[16];
#pragma unroll
    for (int q = 0; q < 16; ++q) accm[q] = b3[ob + q];
#pragma unroll
    for (int m = 0; m < 4; ++m) {
        float cur[8];
        if (m == 0) {
#pragma unroll
            for (int k = 0; k < 8; ++k) cur[k] = a[k];
        } else {
#pragma unroll
            for (int k = 0; k < 8; ++k) cur[k] = __shfl_xor(a[k], m, 64);
        }
        int eb = (c ^ m) * 8;
#pragma unroll
        for (int k = 0; k < 8; ++k) {
            float rk = cur[k];
            const float* wp = &Wl[(eb + k) * 64 + ob];
#pragma unroll
            for (int q = 0; q < 16; ++q) accm[q] += rk * wp[q];
        }
    }
    float s = *a3;
    float px = 0.f, py = 0.f, pz = 0.f, pw = 0.f;
#pragma unroll
    for (int q = 0; q < 16; ++q) {
        float o = prelu_f(accm[q], s) * dvv;
        const float* mp = &Ml[(ob + q) * 4];
        px += o * mp[0]; py += o * mp[1]; pz += o * mp[2]; pw += o * mp[3];
    }
#pragma unroll
    for (int mask = 1; mask <= 2; mask <<= 1) {
        px += __shfl_xor(px, mask, 64);
        py += __shfl_xor(py, mask, 64);
        pz += __shfl_xor(pz, mask, 64);
        pw += __shfl_xor(pw, mask, 64);
    }
    if (c == 0) z[v] = make_float4(px, py, pz, pw);
}

// ---------------- layer-4 aggregation + pooling in z-space (wave-reduced) --------------
__global__ __launch_bounds__(256) void aggpool4_kernel(
    const float4* __restrict__ z, const int* __restrict__ row_off,
    const int* __restrict__ deg, const float* __restrict__ dinv,
    const int* __restrict__ csr_src, const int* __restrict__ batch,
    float* __restrict__ sums, float* __restrict__ cnt, int n) {
    __shared__ float lacc[NG * 4];
    __shared__ float lcnt[NG];
    int tid = threadIdx.x;
    if (tid < NG * 4) lacc[tid] = 0.f;
    if (tid < NG) lcnt[tid] = 0.f;
    __syncthreads();
    int v = blockIdx.x * 256 + tid;
    bool valid = (v < n);
    float cx = 0.f, cy = 0.f, cz = 0.f, cw = 0.f, rc = 0.f;
    int g = -1;
    if (valid) {
        float4 acc = z[v];
        int start = row_off[v], dcnt = deg[v];
        const int* __restrict__ row = csr_src + start;
        int j = 0;
        for (; j + 4 <= dcnt; j += 4) {
            float4 a0 = z[row[j]];
            float4 a1 = z[row[j + 1]];
            float4 a2 = z[row[j + 2]];
            float4 a3 = z[row[j + 3]];
            acc.x += (a0.x + a1.x) + (a2.x + a3.x);
            acc.y += (a0.y + a1.y) + (a2.y + a3.y);
            acc.z += (a0.z + a1.z) + (a2.z + a3.z);
            acc.w += (a0.w + a1.w) + (a2.w + a3.w);
        }
        for (; j < dcnt; ++j) {
            float4 a = z[row[j]];
            acc.x += a.x; acc.y += a.y; acc.z += a.z; acc.w += a.w;
        }
        float dv = dinv[v];
        cx = acc.x * dv; cy = acc.y * dv; cz = acc.z * dv; cw = acc.w * dv;
        rc = 1.f;
        g = batch[v];
    }
    int g0 = __shfl(g, 0, 64);
    if (__all(g == g0 || !valid)) {
#pragma unroll
        for (int mask = 32; mask >= 1; mask >>= 1) {
            cx += __shfl_xor(cx, mask, 64);
            cy += __shfl_xor(cy, mask, 64);
            cz += __shfl_xor(cz, mask, 64);
            cw += __shfl_xor(cw, mask, 64);
            rc += __shfl_xor(rc, mask, 64);
        }
        if ((tid & 63) == 0) {
            float* lp = &lacc[g0 * 4];
            atomicAdd(lp + 0, cx); atomicAdd(lp + 1, cy);
            atomicAdd(lp + 2, cz); atomicAdd(lp + 3, cw);
            atomicAdd(&lcnt[g0], rc);
        }
    } else if (valid) {
        float* lp = &lacc[g * 4];
        atomicAdd(lp + 0, cx); atomicAdd(lp + 1, cy);
        atomicAdd(lp + 2, cz); atomicAdd(lp + 3, cw);
        atomicAdd(&lcnt[g], 1.f);
    }
    __syncthreads();
    if (tid < NG * 4) {
        float val = lacc[tid];
        if (val != 0.f) atomicAdd(&sums[tid], val);
    }
    if (tid < NG) {
        float val = lcnt[tid];
        if (val != 0.f) atomicAdd(&cnt[tid], val);
    }
}

// ---------------- head: out[g][c] = sums[g][c]/cnt[g] + bb[c] ----------------
__global__ void head_kernel(const float* __restrict__ sums, const float* __restrict__ cnt,
                            const float* __restrict__ bb, float* __restrict__ out) {
    int t = threadIdx.x;          // 256 = 64 graphs * 4 classes
    int g = t >> 2, c = t & 3;
    out[t] = sums[t] / fmaxf(cnt[g], 1.f) + bb[c];
}

extern "C" void kernel_launch(void* const* d_in, const int* in_sizes, int n_in,
                              void* d_out, int out_size, void* d_ws, size_t ws_size,
                              hipStream_t stream) {
    const float* x    = (const float*)d_in[0];
    const int* esrc   = (const int*)d_in[1];
    const int* edst   = (const int*)d_in[2];
    const int* batch  = (const int*)d_in[3];
    const float* W1 = (const float*)d_in[4],  *b1 = (const float*)d_in[5];
    const float* W2 = (const float*)d_in[6],  *b2 = (const float*)d_in[7];
    const float* W3 = (const float*)d_in[8],  *b3 = (const float*)d_in[9];
    const float* W4 = (const float*)d_in[10], *b4 = (const float*)d_in[11];
    const float* a1 = (const float*)d_in[12];
    const float* a2 = (const float*)d_in[13];
    const float* a3 = (const float*)d_in[14];
    const float* Wlin = (const float*)d_in[15], *blin = (const float*)d_in[16];
    float* out = (float*)d_out;

    const int N = NN, E = NE;
    const int NB = (N + 1023) / 1024;                   // node-scan blocks (98)
    const int NBIN = (E + BIN_CHUNK - 1) / BIN_CHUNK;   // 196

    // workspace carve-up
    char* w = (char*)d_ws;
    size_t off = 0;
    auto alloc = [&](size_t bytes) { size_t r = off; off += (bytes + 255) & ~(size_t)255; return r; };
    size_t o_bcnt = alloc((size_t)NBUCK * 4);      // needs zero
    size_t o_pool = alloc((size_t)NG * 4 * 4);     // needs zero (pooled z sums)
    size_t o_cnt  = alloc((size_t)NG * 4);         // needs zero
    size_t zero_bytes = off;
    size_t o_deg  = alloc((size_t)N * 4);
    size_t o_dinv = alloc((size_t)N * 4);
    size_t o_roff = alloc((size_t)N * 4);
    size_t o_boff = alloc((size_t)NBUCK * 4);
    size_t o_bcur = alloc((size_t)NBUCK * 4);
    size_t o_bsum = alloc((size_t)128 * 4);
    size_t o_csrc = alloc((size_t)E * 4);
    size_t o_bin  = alloc((size_t)E * 4);          // packed (src<<7)|dst_low
    size_t o_A1   = alloc((size_t)N * 16 * 2);     // layer-1 out fp16 (16 halfs/node)
    size_t o_A2   = alloc((size_t)N * 32 * 2);     // layer-2 out fp16 (32 halfs/node)
    size_t o_z    = alloc((size_t)N * 4 * 4);      // z projections (float4/node)
    size_t o_M    = alloc((size_t)64 * 4 * 4);     // W4@Wlin
    size_t o_bb   = alloc((size_t)4 * 4);          // b4@Wlin + blin
    (void)ws_size;
    int*      bcnt   = (int*)(w + o_bcnt);
    float*    pool   = (float*)(w + o_pool);
    float*    cnt    = (float*)(w + o_cnt);
    int*      deg    = (int*)(w + o_deg);
    float*    dinv   = (float*)(w + o_dinv);
    int*      roff   = (int*)(w + o_roff);
    int*      boff   = (int*)(w + o_boff);
    int*      bcur   = (int*)(w + o_bcur);
    int*      bsum   = (int*)(w + o_bsum);
    int*      csrc   = (int*)(w + o_csrc);
    unsigned* binned = (unsigned*)(w + o_bin);
    float4*   A1     = (float4*)(w + o_A1);
    float4*   A2     = (float4*)(w + o_A2);
    float4*   z      = (float4*)(w + o_z);
    float*    M      = (float*)(w + o_M);
    float*    bb     = (float*)(w + o_bb);

    hipMemsetAsync(w, 0, zero_bytes, stream);

    // ---- head constants (independent; launch early) ----
    makeM_kernel<<<1, 256, 0, stream>>>(W4, b4, Wlin, blin, M, bb);

    // ---- CSR build via dst-bucket binning (once, reused by all 4 layers) ----
    bucket_hist_kernel<<<256, 256, 0, stream>>>(edst, bcnt, E);
    bucket_scan_kernel<<<1, 1024, 0, stream>>>(bcnt, boff, bcur);
    bin_kernel<<<NBIN, 256, 0, stream>>>(esrc, edst, bcur, binned, E);
    deg_dinv_kernel<<<NBUCK, 256, 0, stream>>>(binned, boff, bcnt, deg, dinv, N);
    scan1_kernel<<<NB, 1024, 0, stream>>>(deg, roff, bsum, N);
    scan2_kernel<<<1, 128, 0, stream>>>(bsum, NB);
    scan3_kernel<<<(N + 255) / 256, 256, 0, stream>>>(roff, bsum, N);
    build2_kernel<<<NBUCK, 256, 0, stream>>>(binned, boff, bcnt, roff, csrc, N);

    // ---- layer 1 fused: prescale + agg8 + matmul(8->16) + prelu + dinv ----
    aggmm1_kernel<<<(N * 2 + 255) / 256, 256, 0, stream>>>(
        x, roff, deg, dinv, csrc, W1, b1, a1, A1, N);

    // ---- layer 2 fused: agg16 + matmul(16->32) + prelu + dinv ----
    aggmm2_kernel<<<(N * 2 + 255) / 256, 256, 0, stream>>>(
        A1, roff, deg, dinv, csrc, W2, b2, a2, A2, N);

    // ---- layer 3 fused: agg32 + matmul(32->64) + prelu + dinv + @M -> z ----
    aggmm3_kernel<<<(N * 4 + 255) / 256, 256, 0, stream>>>(
        A2, roff, deg, dinv, csrc, W3, b3, a3, M, z, N);

    // ---- layer 4 in z-space: gather-aggregate + pool over N x 4 (L2-resident) ----
    aggpool4_kernel<<<(N + 255) / 256, 256, 0, stream>>>(
        z, roff, deg, dinv, csrc, batch, pool, cnt, N);
    head_kernel<<<1, 256, 0, stream>>>(pool, cnt, bb, out);
}

// Round 18
// 248.417 us; speedup vs baseline: 1.2131x; 1.0398x over previous
//
#include <hip/hip_runtime.h>
#include <hip/hip_fp16.h>

// Problem constants (match reference file)
#define NN 100000
#define NE 1600000
#define NG 64

// dst-bucketing for the CSR build
#define BSHIFT 7
#define BUCKW (1 << BSHIFT)                 // 128 nodes per bucket
#define NBUCK ((NN + BUCKW - 1) >> BSHIFT)  // 782
#define BIN_CHUNK 8192

// ---- fp16 8-wide helpers (activations stored fp16, math in fp32) ----
union H8 { float4 f4; __half2 h2[4]; };
__device__ __forceinline__ void h8_to_f(const H8& h, float* f) {
    float2 a = __half22float2(h.h2[0]);
    float2 b = __half22float2(h.h2[1]);
    float2 c = __half22float2(h.h2[2]);
    float2 d = __half22float2(h.h2[3]);
    f[0]=a.x; f[1]=a.y; f[2]=b.x; f[3]=b.y; f[4]=c.x; f[5]=c.y; f[6]=d.x; f[7]=d.y;
}
__device__ __forceinline__ H8 f_to_h8(const float* f) {
    H8 h;
    h.h2[0] = __floats2half2_rn(f[0], f[1]);
    h.h2[1] = __floats2half2_rn(f[2], f[3]);
    h.h2[2] = __floats2half2_rn(f[4], f[5]);
    h.h2[3] = __floats2half2_rn(f[6], f[7]);
    return h;
}
__device__ __forceinline__ float prelu_f(float x, float s) {
    return fmaxf(x, 0.f) + s * fminf(x, 0.f);
}

// ---------------- bucket histogram (LDS-aggregated) ----------------
__global__ __launch_bounds__(256) void bucket_hist_kernel(const int* __restrict__ dst,
                                                          int* __restrict__ bucket_cnt, int E) {
    __shared__ int h[NBUCK];
    for (int i = threadIdx.x; i < NBUCK; i += 256) h[i] = 0;
    __syncthreads();
    int stride = gridDim.x * 256;
    for (int e = blockIdx.x * 256 + threadIdx.x; e < E; e += stride)
        atomicAdd(&h[dst[e] >> BSHIFT], 1);
    __syncthreads();
    for (int i = threadIdx.x; i < NBUCK; i += 256)
        if (h[i]) atomicAdd(&bucket_cnt[i], h[i]);
}

// ---------------- bucket scan: single block ----------------
__global__ void bucket_scan_kernel(const int* __restrict__ bcnt, int* __restrict__ boff,
                                   int* __restrict__ bcur) {
    __shared__ int buf[2][1024];
    int t = threadIdx.x;
    int v = (t < NBUCK) ? bcnt[t] : 0;
    buf[0][t] = v;
    __syncthreads();
    int cur = 0;
    for (int off = 1; off < 1024; off <<= 1) {
        int x = buf[cur][t];
        if (t >= off) x += buf[cur][t - off];
        buf[cur ^ 1][t] = x;
        __syncthreads();
        cur ^= 1;
    }
    if (t < NBUCK) {
        int e = buf[cur][t] - v;
        boff[t] = e;
        bcur[t] = e;
    }
}

// ---------------- bin edges by dst-bucket; packed (src<<7)|dst_low ----------------
__global__ __launch_bounds__(256) void bin_kernel(const int* __restrict__ src,
                                                  const int* __restrict__ dst,
                                                  int* __restrict__ bcur,
                                                  unsigned* __restrict__ binned, int E) {
    __shared__ int h[NBUCK];
    __shared__ int cur[NBUCK];
    for (int i = threadIdx.x; i < NBUCK; i += 256) h[i] = 0;
    __syncthreads();
    int base = blockIdx.x * BIN_CHUNK;
    int end = base + BIN_CHUNK; if (end > E) end = E;
    for (int e = base + threadIdx.x; e < end; e += 256)
        atomicAdd(&h[dst[e] >> BSHIFT], 1);
    __syncthreads();
    for (int i = threadIdx.x; i < NBUCK; i += 256) {
        int c = h[i];
        cur[i] = c ? atomicAdd(&bcur[i], c) : 0;   // reserve contiguous sub-range
    }
    __syncthreads();
    for (int e = base + threadIdx.x; e < end; e += 256) {
        unsigned s = (unsigned)src[e], d = (unsigned)dst[e];
        int pos = atomicAdd(&cur[d >> BSHIFT], 1);
        binned[pos] = (s << BSHIFT) | (d & (BUCKW - 1));
    }
}

// ======== fused CSR tail: deg + dinv + roff (bucket-local scan) + csr_src placement ====
// CSR rows are bucket-grouped: roff[v] = boff[bucket] + prefix(deg within bucket).
// One block per bucket: LDS histogram -> LDS 128-scan -> write deg/dinv/roff -> place.
__global__ __launch_bounds__(256) void build_csr_kernel(
    const unsigned* __restrict__ binned, const int* __restrict__ bucket_off,
    const int* __restrict__ bucket_cnt, int* __restrict__ deg, float* __restrict__ dinv,
    int* __restrict__ roff, int* __restrict__ csr_src, int n) {
    __shared__ int ldeg[BUCKW];
    __shared__ int lscan[2][BUCKW];
    __shared__ int lcur[BUCKW];
    int b = blockIdx.x;
    int tid = threadIdx.x;
    for (int i = tid; i < BUCKW; i += 256) ldeg[i] = 0;
    __syncthreads();
    int start = bucket_off[b], cnt = bucket_cnt[b];
    for (int k = tid; k < cnt; k += 256)
        atomicAdd(&ldeg[binned[start + k] & (BUCKW - 1)], 1);
    __syncthreads();
    if (tid < BUCKW) lscan[0][tid] = ldeg[tid];
    __syncthreads();
    int cur = 0;
    for (int off = 1; off < BUCKW; off <<= 1) {
        int x = 0;
        if (tid < BUCKW) {
            x = lscan[cur][tid];
            if (tid >= off) x += lscan[cur][tid - off];
        }
        __syncthreads();
        if (tid < BUCKW) lscan[cur ^ 1][tid] = x;
        __syncthreads();
        cur ^= 1;
    }
    int v0 = b << BSHIFT;
    if (tid < BUCKW) {
        int v = v0 + tid;
        if (v < n) {
            int dg = ldeg[tid];
            deg[v] = dg;
            dinv[v] = rsqrtf((float)dg + 1.0f);   // +1 = self loop
            int r = start + lscan[cur][tid] - dg; // bucket-local exclusive prefix
            roff[v] = r;
            lcur[tid] = r;
        }
    }
    __syncthreads();
    for (int k = tid; k < cnt; k += 256) {
        unsigned e = binned[start + k];
        int pos = atomicAdd(&lcur[e & (BUCKW - 1)], 1);
        csr_src[pos] = (int)(e >> BSHIFT);
    }
}

// ---------------- makeM: M = W4 @ Wlin (64x4), bb = b4 @ Wlin + blin ----------------
__global__ __launch_bounds__(256) void makeM_kernel(
    const float* __restrict__ W4, const float* __restrict__ b4,
    const float* __restrict__ Wlin, const float* __restrict__ blin,
    float* __restrict__ M, float* __restrict__ bb) {
    int t = threadIdx.x;          // 256 = 64 * 4
    int k = t >> 2, c = t & 3;
    float m = 0.f;
    for (int j = 0; j < 128; ++j) m += W4[k * 128 + j] * Wlin[j * 4 + c];
    M[k * 4 + c] = m;
    if (t < 4) {
        float v = blin[t];
        for (int j = 0; j < 128; ++j) v += b4[j] * Wlin[j * 4 + t];
        bb[t] = v;
    }
}

// ======== LAYER 1 fused: prescale + agg(8) + matmul(8->16) + prelu + dinv-scale ========
__global__ __launch_bounds__(256) void aggmm1_kernel(
    const float* __restrict__ x, const int* __restrict__ row_off,
    const int* __restrict__ deg, const float* __restrict__ dinv,
    const int* __restrict__ csr_src, const float* __restrict__ W1,
    const float* __restrict__ b1, const float* __restrict__ a1,
    float4* __restrict__ Aout, int n) {
    __shared__ float Wl[8 * 16];
    for (int i = threadIdx.x; i < 8 * 16; i += 256) Wl[i] = W1[i];
    __syncthreads();
    int idx = blockIdx.x * 256 + threadIdx.x;
    if (idx >= n * 2) return;                 // pairwise-aligned tail: partners agree
    int v = idx >> 1;
    int c = idx & 1;
    const float4* h4 = (const float4*)x;
    float dvv = dinv[v];
    float4 self = h4[(size_t)v * 2 + c];
    float4 acc = make_float4(self.x * dvv, self.y * dvv, self.z * dvv, self.w * dvv);
    int start = row_off[v], cnt = deg[v];
    const int* __restrict__ row = csr_src + start;
    int j = 0;
    for (; j + 4 <= cnt; j += 4) {
        int s0 = row[j], s1 = row[j + 1], s2 = row[j + 2], s3 = row[j + 3];
        float d0 = dinv[s0], d1 = dinv[s1], d2 = dinv[s2], d3 = dinv[s3];
        float4 a0 = h4[(size_t)s0 * 2 + c];
        float4 a1v = h4[(size_t)s1 * 2 + c];
        float4 a2 = h4[(size_t)s2 * 2 + c];
        float4 a3 = h4[(size_t)s3 * 2 + c];
        acc.x += (a0.x * d0 + a1v.x * d1) + (a2.x * d2 + a3.x * d3);
        acc.y += (a0.y * d0 + a1v.y * d1) + (a2.y * d2 + a3.y * d3);
        acc.z += (a0.z * d0 + a1v.z * d1) + (a2.z * d2 + a3.z * d3);
        acc.w += (a0.w * d0 + a1v.w * d1) + (a2.w * d2 + a3.w * d3);
    }
    for (; j < cnt; ++j) {
        int s = row[j];
        float ds = dinv[s];
        float4 a = h4[(size_t)s * 2 + c];
        acc.x += a.x * ds; acc.y += a.y * ds; acc.z += a.z * ds; acc.w += a.w * ds;
    }
    float t[4] = { acc.x * dvv, acc.y * dvv, acc.z * dvv, acc.w * dvv };
    float po[4];
#pragma unroll
    for (int k = 0; k < 4; ++k) po[k] = __shfl_xor(t[k], 1, 64);
    int ob = c * 8;
    int e0 = c * 4, e1 = 4 - e0;
    float accm[8];
#pragma unroll
    for (int q = 0; q < 8; ++q) accm[q] = b1[ob + q];
#pragma unroll
    for (int k = 0; k < 4; ++k) {
        float r1 = t[k], r2 = po[k];
        const float* w1 = &Wl[(e0 + k) * 16 + ob];
        const float* w2 = &Wl[(e1 + k) * 16 + ob];
#pragma unroll
        for (int q = 0; q < 8; ++q) accm[q] += r1 * w1[q] + r2 * w2[q];
    }
    float s = *a1;
    float o[8];
#pragma unroll
    for (int q = 0; q < 8; ++q) o[q] = prelu_f(accm[q], s) * dvv;
    H8 h = f_to_h8(o);
    Aout[(size_t)v * 2 + c] = h.f4;   // A-row = 16 halfs = 2 float4s
}

// ======== LAYER 2 fused: agg(16) + matmul(16->32) + prelu + dinv-scale ========
__global__ __launch_bounds__(256) void aggmm2_kernel(
    const float4* __restrict__ hs, const int* __restrict__ row_off,
    const int* __restrict__ deg, const float* __restrict__ dinv,
    const int* __restrict__ csr_src, const float* __restrict__ W2,
    const float* __restrict__ b2, const float* __restrict__ a2,
    float4* __restrict__ Aout, int n) {
    __shared__ float Wl[16 * 32];   // 2 KB
    for (int i = threadIdx.x; i < 16 * 32; i += 256) Wl[i] = W2[i];
    __syncthreads();
    int idx = blockIdx.x * 256 + threadIdx.x;
    if (idx >= n * 2) return;
    int v = idx >> 1;
    int c = idx & 1;
    float a[8];
    { H8 h; h.f4 = hs[(size_t)v * 2 + c]; h8_to_f(h, a); }
    int start = row_off[v], cnt = deg[v];
    const int* __restrict__ row = csr_src + start;
    int j = 0;
    for (; j + 8 <= cnt; j += 8) {
        H8 hh[8];
#pragma unroll
        for (int q = 0; q < 8; ++q) hh[q].f4 = hs[(size_t)row[j + q] * 2 + c];
#pragma unroll
        for (int q = 0; q < 8; ++q) {
            float f[8]; h8_to_f(hh[q], f);
#pragma unroll
            for (int k = 0; k < 8; ++k) a[k] += f[k];
        }
    }
    for (; j < cnt; ++j) {
        H8 h; h.f4 = hs[(size_t)row[j] * 2 + c];
        float f[8]; h8_to_f(h, f);
#pragma unroll
        for (int k = 0; k < 8; ++k) a[k] += f[k];
    }
    float dvv = dinv[v];
#pragma unroll
    for (int k = 0; k < 8; ++k) a[k] *= dvv;
    float pa[8];
#pragma unroll
    for (int k = 0; k < 8; ++k) pa[k] = __shfl_xor(a[k], 1, 64);
    int ob = c * 16;
    int e0 = c * 8, e1 = 8 - e0;
    float accm[16];
#pragma unroll
    for (int q = 0; q < 16; ++q) accm[q] = b2[ob + q];
#pragma unroll
    for (int k = 0; k < 8; ++k) {
        float r1 = a[k], r2 = pa[k];
        const float* w1 = &Wl[(e0 + k) * 32 + ob];
        const float* w2 = &Wl[(e1 + k) * 32 + ob];
#pragma unroll
        for (int q = 0; q < 16; ++q) accm[q] += r1 * w1[q] + r2 * w2[q];
    }
    float s = *a2;
    float o[16];
#pragma unroll
    for (int q = 0; q < 16; ++q) o[q] = prelu_f(accm[q], s) * dvv;
    H8 h0 = f_to_h8(o);
    H8 h1 = f_to_h8(o + 8);
    Aout[(size_t)v * 4 + c * 2 + 0] = h0.f4;   // A-row = 32 halfs = 4 float4s
    Aout[(size_t)v * 4 + c * 2 + 1] = h1.f4;
}

// ======== LAYER 3 fused: agg(32) + matmul(32->64) + prelu + dinv + @M -> z ========
__global__ __launch_bounds__(256) void aggmm3_kernel(
    const float4* __restrict__ hs, const int* __restrict__ row_off,
    const int* __restrict__ deg, const float* __restrict__ dinv,
    const int* __restrict__ csr_src, const float* __restrict__ W3,
    const float* __restrict__ b3, const float* __restrict__ a3,
    const float* __restrict__ M, float4* __restrict__ z, int n) {
    __shared__ float Wl[32 * 64];   // 8 KB
    __shared__ float Ml[64 * 4];    // 1 KB
    for (int i = threadIdx.x; i < 32 * 64; i += 256) Wl[i] = W3[i];
    for (int i = threadIdx.x; i < 64 * 4; i += 256) Ml[i] = M[i];
    __syncthreads();
    int idx = blockIdx.x * 256 + threadIdx.x;
    if (idx >= n * 4) return;                 // quad-aligned tail
    int v = idx >> 2;
    int c = idx & 3;
    float a[8];
    { H8 h; h.f4 = hs[(size_t)v * 4 + c]; h8_to_f(h, a); }
    int start = row_off[v], cnt = deg[v];
    const int* __restrict__ row = csr_src + start;
    int j = 0;
    for (; j + 8 <= cnt; j += 8) {
        H8 hh[8];
#pragma unroll
        for (int q = 0; q < 8; ++q) hh[q].f4 = hs[(size_t)row[j + q] * 4 + c];
#pragma unroll
        for (int q = 0; q < 8; ++q) {
            float f[8]; h8_to_f(hh[q], f);
#pragma unroll
            for (int k = 0; k < 8; ++k) a[k] += f[k];
        }
    }
    for (; j < cnt; ++j) {
        H8 h; h.f4 = hs[(size_t)row[j] * 4 + c];
        float f[8]; h8_to_f(h, f);
#pragma unroll
        for (int k = 0; k < 8; ++k) a[k] += f[k];
    }
    float dvv = dinv[v];
#pragma unroll
    for (int k = 0; k < 8; ++k) a[k] *= dvv;
    int ob = c * 16;
    float accm[16];
#pragma unroll
    for (int q = 0; q < 16; ++q) accm[q] = b3[ob + q];
#pragma unroll
    for (int m = 0; m < 4; ++m) {
        float cur[8];
        if (m == 0) {
#pragma unroll
            for (int k = 0; k < 8; ++k) cur[k] = a[k];
        } else {
#pragma unroll
            for (int k = 0; k < 8; ++k) cur[k] = __shfl_xor(a[k], m, 64);
        }
        int eb = (c ^ m) * 8;
#pragma unroll
        for (int k = 0; k < 8; ++k) {
            float rk = cur[k];
            const float* wp = &Wl[(eb + k) * 64 + ob];
#pragma unroll
            for (int q = 0; q < 16; ++q) accm[q] += rk * wp[q];
        }
    }
    float s = *a3;
    float px = 0.f, py = 0.f, pz = 0.f, pw = 0.f;
#pragma unroll
    for (int q = 0; q < 16; ++q) {
        float o = prelu_f(accm[q], s) * dvv;
        const float* mp = &Ml[(ob + q) * 4];
        px += o * mp[0]; py += o * mp[1]; pz += o * mp[2]; pw += o * mp[3];
    }
#pragma unroll
    for (int mask = 1; mask <= 2; mask <<= 1) {
        px += __shfl_xor(px, mask, 64);
        py += __shfl_xor(py, mask, 64);
        pz += __shfl_xor(pz, mask, 64);
        pw += __shfl_xor(pw, mask, 64);
    }
    if (c == 0) z[v] = make_float4(px, py, pz, pw);
}

// ---------------- layer-4 aggregation + pooling in z-space (wave-reduced) --------------
__global__ __launch_bounds__(256) void aggpool4_kernel(
    const float4* __restrict__ z, const int* __restrict__ row_off,
    const int* __restrict__ deg, const float* __restrict__ dinv,
    const int* __restrict__ csr_src, const int* __restrict__ batch,
    float* __restrict__ sums, float* __restrict__ cnt, int n) {
    __shared__ float lacc[NG * 4];
    __shared__ float lcnt[NG];
    int tid = threadIdx.x;
    if (tid < NG * 4) lacc[tid] = 0.f;
    if (tid < NG) lcnt[tid] = 0.f;
    __syncthreads();
    int v = blockIdx.x * 256 + tid;
    bool valid = (v < n);
    float cx = 0.f, cy = 0.f, cz = 0.f, cw = 0.f, rc = 0.f;
    int g = -1;
    if (valid) {
        float4 acc = z[v];
        int start = row_off[v], dcnt = deg[v];
        const int* __restrict__ row = csr_src + start;
        int j = 0;
        for (; j + 4 <= dcnt; j += 4) {
            float4 a0 = z[row[j]];
            float4 a1 = z[row[j + 1]];
            float4 a2 = z[row[j + 2]];
            float4 a3 = z[row[j + 3]];
            acc.x += (a0.x + a1.x) + (a2.x + a3.x);
            acc.y += (a0.y + a1.y) + (a2.y + a3.y);
            acc.z += (a0.z + a1.z) + (a2.z + a3.z);
            acc.w += (a0.w + a1.w) + (a2.w + a3.w);
        }
        for (; j < dcnt; ++j) {
            float4 a = z[row[j]];
            acc.x += a.x; acc.y += a.y; acc.z += a.z; acc.w += a.w;
        }
        float dv = dinv[v];
        cx = acc.x * dv; cy = acc.y * dv; cz = acc.z * dv; cw = acc.w * dv;
        rc = 1.f;
        g = batch[v];
    }
    int g0 = __shfl(g, 0, 64);
    if (__all(g == g0 || !valid)) {
#pragma unroll
        for (int mask = 32; mask >= 1; mask >>= 1) {
            cx += __shfl_xor(cx, mask, 64);
            cy += __shfl_xor(cy, mask, 64);
            cz += __shfl_xor(cz, mask, 64);
            cw += __shfl_xor(cw, mask, 64);
            rc += __shfl_xor(rc, mask, 64);
        }
        if ((tid & 63) == 0) {
            float* lp = &lacc[g0 * 4];
            atomicAdd(lp + 0, cx); atomicAdd(lp + 1, cy);
            atomicAdd(lp + 2, cz); atomicAdd(lp + 3, cw);
            atomicAdd(&lcnt[g0], rc);
        }
    } else if (valid) {
        float* lp = &lacc[g * 4];
        atomicAdd(lp + 0, cx); atomicAdd(lp + 1, cy);
        atomicAdd(lp + 2, cz); atomicAdd(lp + 3, cw);
        atomicAdd(&lcnt[g], 1.f);
    }
    __syncthreads();
    if (tid < NG * 4) {
        float val = lacc[tid];
        if (val != 0.f) atomicAdd(&sums[tid], val);
    }
    if (tid < NG) {
        float val = lcnt[tid];
        if (val != 0.f) atomicAdd(&cnt[tid], val);
    }
}

// ---------------- head: out[g][c] = sums[g][c]/cnt[g] + bb[c] ----------------
__global__ void head_kernel(const float* __restrict__ sums, const float* __restrict__ cnt,
                            const float* __restrict__ bb, float* __restrict__ out) {
    int t = threadIdx.x;          // 256 = 64 graphs * 4 classes
    int g = t >> 2, c = t & 3;
    out[t] = sums[t] / fmaxf(cnt[g], 1.f) + bb[c];
}

extern "C" void kernel_launch(void* const* d_in, const int* in_sizes, int n_in,
                              void* d_out, int out_size, void* d_ws, size_t ws_size,
                              hipStream_t stream) {
    const float* x    = (const float*)d_in[0];
    const int* esrc   = (const int*)d_in[1];
    const int* edst   = (const int*)d_in[2];
    const int* batch  = (const int*)d_in[3];
    const float* W1 = (const float*)d_in[4],  *b1 = (const float*)d_in[5];
    const float* W2 = (const float*)d_in[6],  *b2 = (const float*)d_in[7];
    const float* W3 = (const float*)d_in[8],  *b3 = (const float*)d_in[9];
    const float* W4 = (const float*)d_in[10], *b4 = (const float*)d_in[11];
    const float* a1 = (const float*)d_in[12];
    const float* a2 = (const float*)d_in[13];
    const float* a3 = (const float*)d_in[14];
    const float* Wlin = (const float*)d_in[15], *blin = (const float*)d_in[16];
    float* out = (float*)d_out;

    const int N = NN, E = NE;
    const int NBIN = (E + BIN_CHUNK - 1) / BIN_CHUNK;   // 196

    // workspace carve-up
    char* w = (char*)d_ws;
    size_t off = 0;
    auto alloc = [&](size_t bytes) { size_t r = off; off += (bytes + 255) & ~(size_t)255; return r; };
    size_t o_bcnt = alloc((size_t)NBUCK * 4);      // needs zero
    size_t o_pool = alloc((size_t)NG * 4 * 4);     // needs zero (pooled z sums)
    size_t o_cnt  = alloc((size_t)NG * 4);         // needs zero
    size_t zero_bytes = off;
    size_t o_deg  = alloc((size_t)N * 4);
    size_t o_dinv = alloc((size_t)N * 4);
    size_t o_roff = alloc((size_t)N * 4);
    size_t o_boff = alloc((size_t)NBUCK * 4);
    size_t o_bcur = alloc((size_t)NBUCK * 4);
    size_t o_csrc = alloc((size_t)E * 4);
    size_t o_bin  = alloc((size_t)E * 4);          // packed (src<<7)|dst_low
    size_t o_A1   = alloc((size_t)N * 16 * 2);     // layer-1 out fp16 (16 halfs/node)
    size_t o_A2   = alloc((size_t)N * 32 * 2);     // layer-2 out fp16 (32 halfs/node)
    size_t o_z    = alloc((size_t)N * 4 * 4);      // z projections (float4/node)
    size_t o_M    = alloc((size_t)64 * 4 * 4);     // W4@Wlin
    size_t o_bb   = alloc((size_t)4 * 4);          // b4@Wlin + blin
    (void)ws_size;
    int*      bcnt   = (int*)(w + o_bcnt);
    float*    pool   = (float*)(w + o_pool);
    float*    cnt    = (float*)(w + o_cnt);
    int*      deg    = (int*)(w + o_deg);
    float*    dinv   = (float*)(w + o_dinv);
    int*      roff   = (int*)(w + o_roff);
    int*      boff   = (int*)(w + o_boff);
    int*      bcur   = (int*)(w + o_bcur);
    int*      csrc   = (int*)(w + o_csrc);
    unsigned* binned = (unsigned*)(w + o_bin);
    float4*   A1     = (float4*)(w + o_A1);
    float4*   A2     = (float4*)(w + o_A2);
    float4*   z      = (float4*)(w + o_z);
    float*    M      = (float*)(w + o_M);
    float*    bb     = (float*)(w + o_bb);

    hipMemsetAsync(w, 0, zero_bytes, stream);

    // ---- head constants (independent; launch early) ----
    makeM_kernel<<<1, 256, 0, stream>>>(W4, b4, Wlin, blin, M, bb);

    // ---- CSR build via dst-bucket binning (once, reused by all 4 layers) ----
    bucket_hist_kernel<<<256, 256, 0, stream>>>(edst, bcnt, E);
    bucket_scan_kernel<<<1, 1024, 0, stream>>>(bcnt, boff, bcur);
    bin_kernel<<<NBIN, 256, 0, stream>>>(esrc, edst, bcur, binned, E);
    build_csr_kernel<<<NBUCK, 256, 0, stream>>>(binned, boff, bcnt, deg, dinv, roff, csrc, N);

    // ---- layer 1 fused: prescale + agg8 + matmul(8->16) + prelu + dinv ----
    aggmm1_kernel<<<(N * 2 + 255) / 256, 256, 0, stream>>>(
        x, roff, deg, dinv, csrc, W1, b1, a1, A1, N);

    // ---- layer 2 fused: agg16 + matmul(16->32) + prelu + dinv ----
    aggmm2_kernel<<<(N * 2 + 255) / 256, 256, 0, stream>>>(
        A1, roff, deg, dinv, csrc, W2, b2, a2, A2, N);

    // ---- layer 3 fused: agg32 + matmul(32->64) + prelu + dinv + @M -> z ----
    aggmm3_kernel<<<(N * 4 + 255) / 256, 256, 0, stream>>>(
        A2, roff, deg, dinv, csrc, W3, b3, a3, M, z, N);

    // ---- layer 4 in z-space: gather-aggregate + pool over N x 4 (L2-resident) ----
    aggpool4_kernel<<<(N + 255) / 256, 256, 0, stream>>>(
        z, roff, deg, dinv, csrc, batch, pool, cnt, N);
    head_kernel<<<1, 256, 0, stream>>>(pool, cnt, bb, out);
}